// Round 1
// baseline (13530.328 us; speedup 1.0000x reference)
//
#include <hip/hip_runtime.h>
#include <hip/hip_bf16.h>

// Problem dims (fixed by reference)
#define B    128
#define P    196
#define ENC  2048
#define L    50
#define V    10000
#define A_   512
#define D_   512
#define E_   512
#define T_   49
#define XK   3072   // E + ENC + D (x_cat | h)
#define PROJN 2560  // A + ENC

// Output layout (floats)
#define OUT0_OFF 0                      // output [B][T][V]
#define OUT1_OFF 62720000               // caps_s [B][L]
#define OUT2_OFF 62726400               // dec_len [B]
#define OUT3_OFF 62726528               // alphas [B][T][P]
#define OUT4_OFF 63955840               // sort_ind [B]

// Workspace layout (float offsets)
#define WS_SORT   0          // int[128]
#define WS_DLEN   128        // int[128]
#define WS_ACTF   256        // float[128]
#define WS_H      512        // [128][512]
#define WS_C      66048      // [128][512]
#define WS_MEANU  131584     // [128][2048]
#define WS_MEANS  393728     // [128][2048]
#define WS_PROJ   655872     // [128][2560]
#define WS_ALPHA  983552     // [128][196]
#define WS_XCAT   1008640    // [128][3072]
#define WS_GATES  1401856    // 3 slabs of [128][2048]
#define WS_BATTN  2188288    // [2560]
#define WS_BLSTM  2190848    // [2048]
#define WS_EFEAT  2192896    // [128*196][512]

#define BM 128
#define BN 32
#define BK 32

__device__ __forceinline__ float sigmoidf_(float x) { return 1.0f / (1.0f + __expf(-x)); }

// ---------------------------------------------------------------------------
// Stable descending argsort of cap_len (B=128), plus int outputs
// ---------------------------------------------------------------------------
__global__ void sort_kernel(const int* __restrict__ cap_len, const int* __restrict__ enc_cap,
                            int* __restrict__ si, int* __restrict__ dlen,
                            float* __restrict__ out_caps, float* __restrict__ out_dlen,
                            float* __restrict__ out_sind)
{
    __shared__ int cl[B];
    __shared__ int rank_to_idx[B];
    int i = threadIdx.x;
    cl[i] = cap_len[i];
    __syncthreads();
    int my = cl[i];
    int r = 0;
    for (int j = 0; j < B; ++j) {
        int oj = cl[j];
        if (oj > my || (oj == my && j < i)) ++r;
    }
    rank_to_idx[r] = i;
    __syncthreads();
    int src = rank_to_idx[i];
    si[i] = src;
    int dl = cl[src] - 1;
    dlen[i] = dl;
    out_dlen[i] = (float)dl;
    out_sind[i] = (float)src;
    for (int k = 0; k < L; ++k) out_caps[i * L + k] = (float)enc_cap[src * L + k];
}

// ---------------------------------------------------------------------------
// bias concat helpers
// ---------------------------------------------------------------------------
__global__ void bias_cat_kernel(const float* __restrict__ dec_b, const float* __restrict__ fbeta_b,
                                const float* __restrict__ bih, const float* __restrict__ bhh,
                                float* __restrict__ b_attn, float* __restrict__ b_lstm)
{
    int i = blockIdx.x * 256 + threadIdx.x;
    if (i < 512) b_attn[i] = dec_b[i];
    else if (i < 2560) b_attn[i] = fbeta_b[i - 512];
    if (i < 2048) b_lstm[i] = bih[i] + bhh[i];
}

// ---------------------------------------------------------------------------
// mean over P of encoder_out (unsorted), then gather into sorted order
// ---------------------------------------------------------------------------
__global__ void enc_mean_kernel(const float* __restrict__ enc, float* __restrict__ mean_u)
{
    int idx = blockIdx.x * 256 + threadIdx.x;       // B*ENC
    int b = idx >> 11, e = idx & 2047;
    const float* p = enc + (size_t)b * P * ENC + e;
    float s = 0.f;
    for (int q = 0; q < P; ++q) s += p[(size_t)q * ENC];
    mean_u[idx] = s * (1.0f / (float)P);
}

__global__ void gather_mean_kernel(const float* __restrict__ mean_u, const int* __restrict__ si,
                                   float* __restrict__ mean_s)
{
    int idx = blockIdx.x * 256 + threadIdx.x;
    int b = idx >> 11, e = idx & 2047;
    mean_s[idx] = mean_u[(size_t)si[b] * ENC + e];
}

// ---------------------------------------------------------------------------
// Generic f32 GEMM: C[m,n] = sum_k A[m,k] * W(n,k) + bias[n], row-scaled.
// W(n,k) is a virtual view: rows >= nsplit come from Wn2; cols >= ksplit from Wk2.
// Split-K via blockIdx.z (k range [z*KC, (z+1)*KC)), slab outputs; bias on z==0 only.
// ---------------------------------------------------------------------------
__launch_bounds__(256)
__global__ void gemm_nt(const float* __restrict__ Ag, int lda,
                        const float* __restrict__ W1, int ldw1,
                        const float* __restrict__ Wk2, int ldwk2, int ksplit,
                        const float* __restrict__ Wn2, int ldwn2, int nsplit,
                        const float* __restrict__ bias,
                        const float* __restrict__ rowScale,
                        float* __restrict__ C, long long ldc, long long slabStride,
                        int N, int KC)
{
    __shared__ float As[BK][BM];
    __shared__ float Ws[BK][BN];
    const int tid = threadIdx.x;
    const int m0 = blockIdx.y * BM;
    const int n0 = blockIdx.x * BN;
    const int z  = blockIdx.z;
    const int kbeg = z * KC;
    const int kend = kbeg + KC;

    float acc[4][4] = {};
    const int tr = tid >> 3;   // 0..31 -> rows tr*4..+3
    const int tc = tid & 7;    // 0..7  -> cols tc*4..+3

    for (int k0 = kbeg; k0 < kend; k0 += BK) {
        // A tile: 128 rows x 32 k -> 1024 float4, 4 per thread
        #pragma unroll
        for (int i = 0; i < 4; ++i) {
            int linear = tid + i * 256;
            int row = linear >> 3;
            int kv  = linear & 7;
            const float4 v = *reinterpret_cast<const float4*>(&Ag[(size_t)(m0 + row) * lda + k0 + kv * 4]);
            As[kv * 4 + 0][row] = v.x;
            As[kv * 4 + 1][row] = v.y;
            As[kv * 4 + 2][row] = v.z;
            As[kv * 4 + 3][row] = v.w;
        }
        // W tile: 32 n x 32 k -> 256 float4, 1 per thread
        {
            int nrow = tid >> 3;
            int kv   = tid & 7;
            int n = n0 + nrow;
            float4 v = make_float4(0.f, 0.f, 0.f, 0.f);
            if (n < N) {
                int k = k0 + kv * 4;
                const float* wp;
                if (n >= nsplit)      wp = Wn2 + (size_t)(n - nsplit) * ldwn2 + k;
                else if (k >= ksplit) wp = Wk2 + (size_t)n * ldwk2 + (k - ksplit);
                else                  wp = W1 + (size_t)n * ldw1 + k;
                v = *reinterpret_cast<const float4*>(wp);
            }
            Ws[kv * 4 + 0][nrow] = v.x;
            Ws[kv * 4 + 1][nrow] = v.y;
            Ws[kv * 4 + 2][nrow] = v.z;
            Ws[kv * 4 + 3][nrow] = v.w;
        }
        __syncthreads();
        #pragma unroll
        for (int kk = 0; kk < BK; ++kk) {
            float4 a4 = *reinterpret_cast<const float4*>(&As[kk][tr * 4]);
            float4 w4 = *reinterpret_cast<const float4*>(&Ws[kk][tc * 4]);
            float av[4] = {a4.x, a4.y, a4.z, a4.w};
            float wv[4] = {w4.x, w4.y, w4.z, w4.w};
            #pragma unroll
            for (int i = 0; i < 4; ++i)
                #pragma unroll
                for (int j = 0; j < 4; ++j)
                    acc[i][j] = fmaf(av[i], wv[j], acc[i][j]);
        }
        __syncthreads();
    }

    float* Cz = C + (size_t)z * slabStride;
    #pragma unroll
    for (int i = 0; i < 4; ++i) {
        int m = m0 + tr * 4 + i;
        float rs = rowScale ? rowScale[m] : 1.0f;
        #pragma unroll
        for (int j = 0; j < 4; ++j) {
            int n = n0 + tc * 4 + j;
            if (n < N) {
                float vv = acc[i][j];
                if (bias && z == 0) vv += bias[n];
                vv *= rs;
                Cz[(size_t)m * ldc + n] = vv;
            }
        }
    }
}

// ---------------------------------------------------------------------------
// scores + softmax + alpha + x_cat(emb,h) + active flag. One block per b.
// ---------------------------------------------------------------------------
__global__ void scores_softmax_kernel(const float* __restrict__ enc_feat,  // [B*P][A] unsorted
                                      const float* __restrict__ proj,      // [B][2560]
                                      const float* __restrict__ full_W,    // [A]
                                      const float* __restrict__ full_b,    // [1]
                                      const int* __restrict__ si, const int* __restrict__ dlen,
                                      const int* __restrict__ enc_cap, const float* __restrict__ emb_W,
                                      const float* __restrict__ h,
                                      float* __restrict__ alpha_ws, float* __restrict__ alphas_out,
                                      float* __restrict__ x_cat, float* __restrict__ active_f, int t)
{
    int b = blockIdx.x;
    int tid = threadIdx.x;
    __shared__ float df[A_];
    __shared__ float sc[P];
    __shared__ float red[8];
    int sb = si[b];
    for (int i = tid; i < A_; i += 256) df[i] = proj[(size_t)b * PROJN + i];
    __syncthreads();
    int wave = tid >> 6, lane = tid & 63;
    const float fb = full_b[0];
    for (int p = wave; p < P; p += 4) {
        const float* ef = enc_feat + ((size_t)(sb * P + p)) * A_;
        float s = 0.f;
        #pragma unroll
        for (int i = 0; i < 8; ++i) {
            int a = lane + i * 64;
            float vv = ef[a] + df[a];
            vv = vv > 0.f ? vv : 0.f;
            s += vv * full_W[a];
        }
        for (int off = 32; off; off >>= 1) s += __shfl_down(s, off);
        if (lane == 0) sc[p] = s + fb;
    }
    __syncthreads();
    // block max
    float m = -1e30f;
    for (int p = tid; p < P; p += 256) m = fmaxf(m, sc[p]);
    for (int off = 32; off; off >>= 1) m = fmaxf(m, __shfl_down(m, off));
    if (lane == 0) red[wave] = m;
    __syncthreads();
    if (tid == 0) {
        float mm = red[0];
        for (int w = 1; w < 4; ++w) mm = fmaxf(mm, red[w]);
        red[4] = mm;
    }
    __syncthreads();
    m = red[4];
    float ssum = 0.f;
    for (int p = tid; p < P; p += 256) { float e = __expf(sc[p] - m); sc[p] = e; ssum += e; }
    for (int off = 32; off; off >>= 1) ssum += __shfl_down(ssum, off);
    if (lane == 0) red[wave] = ssum;
    __syncthreads();
    if (tid == 0) {
        float s2 = 0.f;
        for (int w = 0; w < 4; ++w) s2 += red[w];
        red[5] = 1.0f / s2;
    }
    __syncthreads();
    float inv = red[5];
    int active = dlen[b] > t;
    float af = active ? 1.0f : 0.0f;
    for (int p = tid; p < P; p += 256) {
        float a = sc[p] * inv;
        alpha_ws[b * P + p] = a;                                   // unmasked, for ctx
        alphas_out[((size_t)b * T_ + t) * P + p] = a * af;         // masked output
    }
    // fill x_cat: emb slot + h slot
    int tok = enc_cap[sb * L + t];
    for (int k = tid; k < E_; k += 256) {
        x_cat[(size_t)b * XK + k]        = emb_W[(size_t)tok * E_ + k];
        x_cat[(size_t)b * XK + 2560 + k] = h[(size_t)b * D_ + k];
    }
    if (tid == 0) active_f[b] = af;
}

// ---------------------------------------------------------------------------
// ctx[b,e] = sigmoid(gate_lin[b,e]) * sum_p alpha[b,p]*enc[sb,p,e] -> x_cat ctx slot
// grid (8, 128): blockIdx.x = e-chunk, blockIdx.y = b
// ---------------------------------------------------------------------------
__global__ void ctx_kernel(const float* __restrict__ enc, const float* __restrict__ alpha_ws,
                           const float* __restrict__ proj, const int* __restrict__ si,
                           float* __restrict__ x_cat)
{
    int b = blockIdx.y;
    int e = blockIdx.x * 256 + threadIdx.x;   // e < 2048
    __shared__ float al[P];
    for (int p = threadIdx.x; p < P; p += 256) al[p] = alpha_ws[b * P + p];
    __syncthreads();
    int sb = si[b];
    const float* eb = enc + (size_t)sb * P * ENC + e;
    float acc = 0.f;
    #pragma unroll 4
    for (int p = 0; p < P; ++p) acc = fmaf(al[p], eb[(size_t)p * ENC], acc);
    float g = sigmoidf_(proj[(size_t)b * PROJN + A_ + e]);
    x_cat[(size_t)b * XK + E_ + e] = acc * g;
}

// ---------------------------------------------------------------------------
// LSTM pointwise: sum 3 split-K slabs, gate nonlinearities, masked state update
// ---------------------------------------------------------------------------
__global__ void lstm_pointwise_kernel(const float* __restrict__ gates, const float* __restrict__ active_f,
                                      float* __restrict__ h, float* __restrict__ c)
{
    int idx = blockIdx.x * 256 + threadIdx.x;  // B*D
    int b = idx >> 9, d = idx & 511;
    const size_t slab = (size_t)B * 2048;
    const float* g0 = gates + (size_t)b * 2048;
    float gi = g0[d]        + g0[slab + d]        + g0[2 * slab + d];
    float gf = g0[512 + d]  + g0[slab + 512 + d]  + g0[2 * slab + 512 + d];
    float gg = g0[1024 + d] + g0[slab + 1024 + d] + g0[2 * slab + 1024 + d];
    float go = g0[1536 + d] + g0[slab + 1536 + d] + g0[2 * slab + 1536 + d];
    float a = active_f[b];
    float cn = sigmoidf_(gf) * c[idx] + sigmoidf_(gi) * tanhf(gg);
    float hn = sigmoidf_(go) * tanhf(cn);
    h[idx] = a * hn + (1.0f - a) * h[idx];
    c[idx] = a * cn + (1.0f - a) * c[idx];
}

// ---------------------------------------------------------------------------
extern "C" void kernel_launch(void* const* d_in, const int* in_sizes, int n_in,
                              void* d_out, int out_size, void* d_ws, size_t ws_size,
                              hipStream_t stream)
{
    const float* encoder_out = (const float*)d_in[0];
    const int*   enc_cap     = (const int*)d_in[1];
    const int*   cap_len     = (const int*)d_in[2];
    const float* emb_W       = (const float*)d_in[3];
    const float* init_h_W    = (const float*)d_in[4];
    const float* init_h_b    = (const float*)d_in[5];
    const float* init_c_W    = (const float*)d_in[6];
    const float* init_c_b    = (const float*)d_in[7];
    const float* enc_attn_W  = (const float*)d_in[8];
    const float* enc_attn_b  = (const float*)d_in[9];
    const float* dec_attn_W  = (const float*)d_in[10];
    const float* dec_attn_b  = (const float*)d_in[11];
    const float* full_attn_W = (const float*)d_in[12];
    const float* full_attn_b = (const float*)d_in[13];
    const float* lstm_Wih    = (const float*)d_in[14];
    const float* lstm_Whh    = (const float*)d_in[15];
    const float* lstm_bih    = (const float*)d_in[16];
    const float* lstm_bhh    = (const float*)d_in[17];
    const float* fbeta_W     = (const float*)d_in[18];
    const float* fbeta_b     = (const float*)d_in[19];
    const float* fc_W        = (const float*)d_in[20];
    const float* fc_b        = (const float*)d_in[21];

    float* ws = (float*)d_ws;
    int*   si    = (int*)(ws + WS_SORT);
    int*   dlen  = (int*)(ws + WS_DLEN);
    float* actf  = ws + WS_ACTF;
    float* h     = ws + WS_H;
    float* c     = ws + WS_C;
    float* meanu = ws + WS_MEANU;
    float* means = ws + WS_MEANS;
    float* proj  = ws + WS_PROJ;
    float* alpha = ws + WS_ALPHA;
    float* xcat  = ws + WS_XCAT;
    float* gates = ws + WS_GATES;
    float* battn = ws + WS_BATTN;
    float* blstm = ws + WS_BLSTM;
    float* efeat = ws + WS_EFEAT;

    float* out      = (float*)d_out;
    float* out0     = out + OUT0_OFF;
    float* out_caps = out + OUT1_OFF;
    float* out_dlen = out + OUT2_OFF;
    float* alphas   = out + OUT3_OFF;
    float* out_sind = out + OUT4_OFF;

    const int BIG = 1 << 30;

    // ---- setup ----
    sort_kernel<<<1, B, 0, stream>>>(cap_len, enc_cap, si, dlen, out_caps, out_dlen, out_sind);
    bias_cat_kernel<<<10, 256, 0, stream>>>(dec_attn_b, fbeta_b, lstm_bih, lstm_bhh, battn, blstm);
    enc_mean_kernel<<<(B * ENC) / 256, 256, 0, stream>>>(encoder_out, meanu);
    gather_mean_kernel<<<(B * ENC) / 256, 256, 0, stream>>>(meanu, si, means);

    // h0 = means @ init_h_W.T + b ; c0 likewise
    gemm_nt<<<dim3(D_ / BN, 1, 1), 256, 0, stream>>>(
        means, ENC, init_h_W, ENC, nullptr, 0, BIG, nullptr, 0, BIG,
        init_h_b, nullptr, h, D_, 0, D_, ENC);
    gemm_nt<<<dim3(D_ / BN, 1, 1), 256, 0, stream>>>(
        means, ENC, init_c_W, ENC, nullptr, 0, BIG, nullptr, 0, BIG,
        init_c_b, nullptr, c, D_, 0, D_, ENC);

    // enc_feat (unsorted) = encoder_out @ enc_attn_W.T + b : [B*P][A]
    gemm_nt<<<dim3(A_ / BN, (B * P) / BM, 1), 256, 0, stream>>>(
        encoder_out, ENC, enc_attn_W, ENC, nullptr, 0, BIG, nullptr, 0, BIG,
        enc_attn_b, nullptr, efeat, A_, 0, A_, ENC);

    // ---- decode loop ----
    for (int t = 0; t < T_; ++t) {
        // proj = h @ [dec_attn_W ; fbeta_W].T + [dec_b ; fbeta_b]  -> [B][2560]
        gemm_nt<<<dim3(PROJN / BN, 1, 1), 256, 0, stream>>>(
            h, D_, dec_attn_W, D_, nullptr, 0, BIG, fbeta_W, D_, A_,
            battn, nullptr, proj, PROJN, 0, PROJN, D_);

        scores_softmax_kernel<<<B, 256, 0, stream>>>(
            efeat, proj, full_attn_W, full_attn_b, si, dlen, enc_cap, emb_W, h,
            alpha, alphas, xcat, actf, t);

        ctx_kernel<<<dim3(ENC / 256, B, 1), 256, 0, stream>>>(
            encoder_out, alpha, proj, si, xcat);

        // gates = x_cat @ [Wih | Whh].T + (bih+bhh), split-K = 3 slabs of 1024
        gemm_nt<<<dim3(2048 / BN, 1, 3), 256, 0, stream>>>(
            xcat, XK, lstm_Wih, 2560, lstm_Whh, D_, 2560, nullptr, 0, BIG,
            blstm, nullptr, gates, 2048, (long long)B * 2048, 2048, 1024);

        lstm_pointwise_kernel<<<(B * D_) / 256, 256, 0, stream>>>(gates, actf, h, c);

        // out[:, t, :] = (h @ fc_W.T + fc_b) * active
        gemm_nt<<<dim3((V + BN - 1) / BN, 1, 1), 256, 0, stream>>>(
            h, D_, fc_W, D_, nullptr, 0, BIG, nullptr, 0, BIG,
            fc_b, actf, out0 + (size_t)t * V, (long long)T_ * V, 0, V, D_);
    }
}

// Round 2
// 6362.572 us; speedup vs baseline: 2.1266x; 2.1266x over previous
//
#include <hip/hip_runtime.h>
#include <hip/hip_bf16.h>

// Problem dims
#define B_    128
#define P_    196
#define ENCD  2048
#define LL    50
#define VV    10000
#define AA    512
#define DD    512
#define EE    512
#define TT    49
#define XKK   3072    // E + ENC + D
#define PROJN 2560    // A + ENC
#define VPAD  10048   // V rounded up to 64

// Output layout (float offsets)
#define OUT0_OFF 0
#define OUT1_OFF 62720000
#define OUT2_OFF 62726400
#define OUT3_OFF 62726528
#define OUT4_OFF 63955840

// Workspace layout (BYTE offsets)
#define WS_SI      0ull
#define WS_DLEN    512ull
#define WS_BATTN   1024ull
#define WS_BLSTM   11264ull
#define WS_MEANS   19456ull
#define WS_H       1068032ull
#define WS_C       1330176ull
#define WS_HBF     1592320ull
#define WS_PROJ    1723392ull
#define WS_ALPHA   3034112ull
#define WS_XCAT    3134464ull
#define WS_GATES   3920896ull
#define WS_HSTORE  4969472ull
#define WS_WPROJ   11392000ull
#define WS_WCAT    14013440ull
#define WS_FCW     26596352ull
#define WS_EFEAT   36885504ull
#define WS_ENCBF   62575616ull
#define NEED_ENCBF 165336064ull

typedef __attribute__((ext_vector_type(4))) float f32x4;
typedef __attribute__((ext_vector_type(8))) short s16x8;

__device__ __forceinline__ float sigmoidf_(float x) { return 1.0f / (1.0f + __expf(-x)); }

__device__ __forceinline__ unsigned short f2bf(float x) {
    union { float f; unsigned int u; } v; v.f = x;
    unsigned int r = (v.u + 0x7FFFu + ((v.u >> 16) & 1u)) >> 16;
    return (unsigned short)r;
}
__device__ __forceinline__ float bf2f(unsigned short u) {
    return __uint_as_float(((unsigned int)u) << 16);
}

__device__ __forceinline__ void gload_lds16(const void* g, void* l) {
    __builtin_amdgcn_global_load_lds((const __attribute__((address_space(1))) void*)g,
                                     (__attribute__((address_space(3))) void*)l, 16, 0, 0);
}

// ---------------------------------------------------------------------------
// Stable descending argsort of cap_len (B=128), plus int-ish outputs
// ---------------------------------------------------------------------------
__global__ void sort_kernel(const int* __restrict__ cap_len, const int* __restrict__ enc_cap,
                            int* __restrict__ si, int* __restrict__ dlen,
                            float* __restrict__ out_caps, float* __restrict__ out_dlen,
                            float* __restrict__ out_sind)
{
    __shared__ int cl[B_];
    __shared__ int rank_to_idx[B_];
    int i = threadIdx.x;
    cl[i] = cap_len[i];
    __syncthreads();
    int my = cl[i];
    int r = 0;
    for (int j = 0; j < B_; ++j) {
        int oj = cl[j];
        if (oj > my || (oj == my && j < i)) ++r;
    }
    rank_to_idx[r] = i;
    __syncthreads();
    int src = rank_to_idx[i];
    si[i] = src;
    int dl = cl[src] - 1;
    dlen[i] = dl;
    out_dlen[i] = (float)dl;
    out_sind[i] = (float)src;
    for (int k = 0; k < LL; ++k) out_caps[i * LL + k] = (float)enc_cap[src * LL + k];
}

__global__ void bias_cat_kernel(const float* __restrict__ dec_b, const float* __restrict__ fbeta_b,
                                const float* __restrict__ bih, const float* __restrict__ bhh,
                                float* __restrict__ b_attn, float* __restrict__ b_lstm)
{
    int i = blockIdx.x * 256 + threadIdx.x;
    if (i < AA) b_attn[i] = dec_b[i];
    else if (i < PROJN) b_attn[i] = fbeta_b[i - AA];
    if (i < 2048) b_lstm[i] = bih[i] + bhh[i];
}

// means[b] = mean over P of enc[si[b]]
__global__ void enc_mean_sorted(const float* __restrict__ enc, const int* __restrict__ si,
                                float* __restrict__ means)
{
    int idx = blockIdx.x * 256 + threadIdx.x;   // B*ENC
    int b = idx >> 11, e = idx & 2047;
    const float* p = enc + (size_t)si[b] * P_ * ENCD + e;
    float s = 0.f;
    for (int q = 0; q < P_; ++q) s += p[(size_t)q * ENCD];
    means[idx] = s * (1.0f / 196.0f);
}

// ---------------------------------------------------------------------------
// f32 GEMM (round-1 kernel, kept for the two small one-time init GEMMs)
// ---------------------------------------------------------------------------
#define BM 128
#define BN 32
#define BK 32
__launch_bounds__(256)
__global__ void gemm_nt(const float* __restrict__ Ag, int lda,
                        const float* __restrict__ W1, int ldw1,
                        const float* __restrict__ bias,
                        float* __restrict__ C, int ldc, int N, int K)
{
    __shared__ float As[BK][BM];
    __shared__ float Ws[BK][BN];
    const int tid = threadIdx.x;
    const int n0 = blockIdx.x * BN;
    float acc[4][4] = {};
    const int tr = tid >> 3;
    const int tc = tid & 7;
    for (int k0 = 0; k0 < K; k0 += BK) {
        #pragma unroll
        for (int i = 0; i < 4; ++i) {
            int linear = tid + i * 256;
            int row = linear >> 3;
            int kv  = linear & 7;
            const float4 v = *reinterpret_cast<const float4*>(&Ag[(size_t)row * lda + k0 + kv * 4]);
            As[kv * 4 + 0][row] = v.x; As[kv * 4 + 1][row] = v.y;
            As[kv * 4 + 2][row] = v.z; As[kv * 4 + 3][row] = v.w;
        }
        {
            int nrow = tid >> 3;
            int kv   = tid & 7;
            const float4 v = *reinterpret_cast<const float4*>(&W1[(size_t)(n0 + nrow) * ldw1 + k0 + kv * 4]);
            Ws[kv * 4 + 0][nrow] = v.x; Ws[kv * 4 + 1][nrow] = v.y;
            Ws[kv * 4 + 2][nrow] = v.z; Ws[kv * 4 + 3][nrow] = v.w;
        }
        __syncthreads();
        #pragma unroll
        for (int kk = 0; kk < BK; ++kk) {
            float4 a4 = *reinterpret_cast<const float4*>(&As[kk][tr * 4]);
            float4 w4 = *reinterpret_cast<const float4*>(&Ws[kk][tc * 4]);
            float av[4] = {a4.x, a4.y, a4.z, a4.w};
            float wv[4] = {w4.x, w4.y, w4.z, w4.w};
            #pragma unroll
            for (int i = 0; i < 4; ++i)
                #pragma unroll
                for (int j = 0; j < 4; ++j)
                    acc[i][j] = fmaf(av[i], wv[j], acc[i][j]);
        }
        __syncthreads();
    }
    #pragma unroll
    for (int i = 0; i < 4; ++i) {
        int m = tr * 4 + i;
        #pragma unroll
        for (int j = 0; j < 4; ++j) {
            int n = n0 + tc * 4 + j;
            C[(size_t)m * ldc + n] = acc[i][j] + bias[n];
        }
    }
}

// ---------------------------------------------------------------------------
// bf16 MFMA GEMM: C[M,N] = A[M,K] @ W[N,K]^T + bias
// BM=128, BN=64, BK=32; 4 waves; wave w owns n-slice w*16..+15, full 128 m.
// MODE 0: f32 out (ldc);  MODE 1: bf16 out (ldc);
// MODE 2: fc epilogue — m=(t*128+b), out[(b*49+t)*10000+n] masked by dlen[b]>t, n<Nreal.
// CONV: A and W are f32 sources, converted to bf16 during reg-staging.
// ---------------------------------------------------------------------------
template<int MODE, bool CONV>
__launch_bounds__(256)
__global__ void mfma_gemm(const void* __restrict__ Av, const void* __restrict__ Wv,
                          const float* __restrict__ bias, const int* __restrict__ dlen,
                          float* __restrict__ Cf, unsigned short* __restrict__ Cbf,
                          int K, int ldc, int Nreal)
{
    __shared__ __align__(16) unsigned short As[128 * 32];
    __shared__ __align__(16) unsigned short Ws[64 * 32];
    const int tid  = threadIdx.x;
    const int wave = tid >> 6, lane = tid & 63;
    const int m0 = blockIdx.y * 128;
    const int n0 = blockIdx.x * 64;
    const int r16 = lane & 15, kg = lane >> 4;

    f32x4 acc[8];
    #pragma unroll
    for (int i = 0; i < 8; ++i) acc[i] = f32x4{0.f, 0.f, 0.f, 0.f};

    // staging geometry (bf16 path)
    const int a_off0 = wave * 2048 + lane * 16;          // byte offset in As
    const int a_row0 = a_off0 >> 6, a_c0 = (a_off0 >> 4) & 3;
    const int a_off1 = a_off0 + 1024;
    const int a_row1 = a_off1 >> 6, a_c1 = (a_off1 >> 4) & 3;
    const int w_off  = wave * 1024 + lane * 16;
    const int w_row  = w_off >> 6,  w_c  = (w_off >> 4) & 3;

    for (int k0 = 0; k0 < K; k0 += 32) {
        if constexpr (!CONV) {
            const unsigned short* A = (const unsigned short*)Av;
            const unsigned short* W = (const unsigned short*)Wv;
            gload_lds16(A + (size_t)(m0 + a_row0) * K + k0 + a_c0 * 8, As + wave * 1024);
            gload_lds16(A + (size_t)(m0 + a_row1) * K + k0 + a_c1 * 8, As + wave * 1024 + 512);
            gload_lds16(W + (size_t)(n0 + w_row)  * K + k0 + w_c  * 8, Ws + wave * 512);
        } else {
            const float* A = (const float*)Av;
            const float* W = (const float*)Wv;
            int row = tid >> 1, cbase = (tid & 1) * 16;
            unsigned short tmp[16];
            #pragma unroll
            for (int j = 0; j < 16; ++j) tmp[j] = f2bf(A[(size_t)(m0 + row) * K + k0 + cbase + j]);
            *(s16x8*)&As[row * 32 + cbase]     = *(s16x8*)&tmp[0];
            *(s16x8*)&As[row * 32 + cbase + 8] = *(s16x8*)&tmp[8];
            int wr = tid >> 2, wcb = (tid & 3) * 8;
            unsigned short tw[8];
            #pragma unroll
            for (int j = 0; j < 8; ++j) tw[j] = f2bf(W[(size_t)(n0 + wr) * K + k0 + wcb + j]);
            *(s16x8*)&Ws[wr * 32 + wcb] = *(s16x8*)&tw[0];
        }
        __syncthreads();
        s16x8 bfrag = *(const s16x8*)&Ws[(wave * 16 + r16) * 32 + kg * 8];
        #pragma unroll
        for (int i = 0; i < 8; ++i) {
            s16x8 afrag = *(const s16x8*)&As[(i * 16 + r16) * 32 + kg * 8];
            acc[i] = __builtin_amdgcn_mfma_f32_16x16x32_bf16(afrag, bfrag, acc[i], 0, 0, 0);
        }
        __syncthreads();
    }

    int n = n0 + wave * 16 + r16;
    float bv = (MODE == 2) ? (n < Nreal ? bias[n] : 0.f) : bias[n];
    #pragma unroll
    for (int i = 0; i < 8; ++i) {
        #pragma unroll
        for (int r = 0; r < 4; ++r) {
            int m = m0 + i * 16 + kg * 4 + r;
            float v = acc[i][r] + bv;
            if (MODE == 0) {
                Cf[(size_t)m * ldc + n] = v;
            } else if (MODE == 1) {
                Cbf[(size_t)m * ldc + n] = f2bf(v);
            } else {
                int bb = m & 127, tt2 = m >> 7;
                if (n < Nreal)
                    Cf[((size_t)bb * TT + tt2) * VV + n] = (dlen[bb] > tt2) ? v : 0.f;
            }
        }
    }
}

// ---------------------------------------------------------------------------
// scores + softmax + alpha + x_cat(emb,h). One block per b.
// ---------------------------------------------------------------------------
__global__ void scores_kernel(const unsigned short* __restrict__ efeat, const float* __restrict__ proj,
                              const float* __restrict__ full_W, const float* __restrict__ full_b,
                              const int* __restrict__ si, const int* __restrict__ dlen,
                              const int* __restrict__ enc_cap, const float* __restrict__ emb_W,
                              const unsigned short* __restrict__ h_bf,
                              float* __restrict__ alpha_ws, float* __restrict__ alphas_out,
                              unsigned short* __restrict__ xcat, int t)
{
    int b = blockIdx.x, tid = threadIdx.x;
    int wave = tid >> 6, lane = tid & 63;
    __shared__ float df[AA];
    __shared__ float wf[AA];
    __shared__ float sc[P_];
    __shared__ float red[8];
    int sb = si[b];
    for (int i = tid; i < AA; i += 256) { df[i] = proj[(size_t)b * PROJN + i]; wf[i] = full_W[i]; }
    __syncthreads();
    const float fb = full_b[0];
    float dfv[8], wfv[8];
    #pragma unroll
    for (int j = 0; j < 8; ++j) { dfv[j] = df[lane * 8 + j]; wfv[j] = wf[lane * 8 + j]; }
    for (int p = wave; p < P_; p += 4) {
        const unsigned short* ef = efeat + ((size_t)sb * P_ + p) * AA + lane * 8;
        s16x8 ev = *(const s16x8*)ef;
        float s = 0.f;
        #pragma unroll
        for (int j = 0; j < 8; ++j) {
            float e = bf2f((unsigned short)ev[j]);
            float v = e + dfv[j];
            v = v > 0.f ? v : 0.f;
            s += v * wfv[j];
        }
        #pragma unroll
        for (int off = 32; off; off >>= 1) s += __shfl_down(s, off);
        if (lane == 0) sc[p] = s + fb;
    }
    __syncthreads();
    float m = -1e30f;
    for (int p = tid; p < P_; p += 256) m = fmaxf(m, sc[p]);
    for (int off = 32; off; off >>= 1) m = fmaxf(m, __shfl_down(m, off));
    if (lane == 0) red[wave] = m;
    __syncthreads();
    if (tid == 0) {
        float mm = red[0];
        for (int w = 1; w < 4; ++w) mm = fmaxf(mm, red[w]);
        red[4] = mm;
    }
    __syncthreads();
    m = red[4];
    float ssum = 0.f;
    for (int p = tid; p < P_; p += 256) { float e = __expf(sc[p] - m); sc[p] = e; ssum += e; }
    for (int off = 32; off; off >>= 1) ssum += __shfl_down(ssum, off);
    if (lane == 0) red[wave] = ssum;
    __syncthreads();
    if (tid == 0) {
        float s2 = 0.f;
        for (int w = 0; w < 4; ++w) s2 += red[w];
        red[5] = 1.0f / s2;
    }
    __syncthreads();
    float inv = red[5];
    float af = (dlen[b] > t) ? 1.0f : 0.0f;
    for (int p = tid; p < P_; p += 256) {
        float a = sc[p] * inv;
        alpha_ws[b * P_ + p] = a;
        alphas_out[((size_t)b * TT + t) * P_ + p] = a * af;
    }
    int tok = enc_cap[sb * LL + t];
    for (int k = tid; k < EE; k += 256) {
        xcat[(size_t)b * XKK + k]        = f2bf(emb_W[(size_t)tok * EE + k]);
        xcat[(size_t)b * XKK + 2560 + k] = h_bf[b * DD + k];
    }
}

// ---------------------------------------------------------------------------
// ctx: x_cat[b, 512+e] = bf16( sigmoid(proj[b,512+e]) * sum_p alpha[b,p]*enc[sb,p,e] )
// grid (4, 128); each thread handles 2 consecutive e.
// ---------------------------------------------------------------------------
__global__ void ctx_kernel(const float* __restrict__ encf, const unsigned short* __restrict__ encbf,
                           const int use_bf,
                           const float* __restrict__ alpha_ws, const float* __restrict__ proj,
                           const int* __restrict__ si, unsigned short* __restrict__ xcat)
{
    int b = blockIdx.y, tid = threadIdx.x;
    int e0 = blockIdx.x * 512 + tid * 2;
    __shared__ float al[P_];
    for (int p = tid; p < P_; p += 256) al[p] = alpha_ws[b * P_ + p];
    __syncthreads();
    int sb = si[b];
    float a0 = 0.f, a1 = 0.f;
    if (use_bf) {
        const unsigned short* pe = encbf + (size_t)sb * P_ * ENCD + e0;
        #pragma unroll 4
        for (int p = 0; p < P_; ++p) {
            unsigned int u = *(const unsigned int*)(pe + (size_t)p * ENCD);
            a0 = fmaf(al[p], __uint_as_float(u << 16), a0);
            a1 = fmaf(al[p], __uint_as_float(u & 0xffff0000u), a1);
        }
    } else {
        const float* pe = encf + (size_t)sb * P_ * ENCD + e0;
        #pragma unroll 4
        for (int p = 0; p < P_; ++p) {
            float2 v = *(const float2*)(pe + (size_t)p * ENCD);
            a0 = fmaf(al[p], v.x, a0);
            a1 = fmaf(al[p], v.y, a1);
        }
    }
    float g0 = sigmoidf_(proj[(size_t)b * PROJN + AA + e0]);
    float g1 = sigmoidf_(proj[(size_t)b * PROJN + AA + e0 + 1]);
    unsigned int pk = (unsigned int)f2bf(a0 * g0) | ((unsigned int)f2bf(a1 * g1) << 16);
    *(unsigned int*)&xcat[(size_t)b * XKK + EE + e0] = pk;
}

// ---------------------------------------------------------------------------
// LSTM pointwise for step (t-1): gates -> h,c (frozen past dec_len), h_bf, hstore[t-1]
// ---------------------------------------------------------------------------
__global__ void pointwise_kernel(const float* __restrict__ gates, const int* __restrict__ dlen,
                                 float* __restrict__ h, float* __restrict__ c,
                                 unsigned short* __restrict__ h_bf, unsigned short* __restrict__ hstore,
                                 int t)
{
    int idx = blockIdx.x * 256 + threadIdx.x;   // B*D
    int b = idx >> 9, d = idx & 511;
    const float* g = gates + (size_t)b * 2048;
    float gi = g[d], gf = g[d + 512], gg = g[d + 1024], go = g[d + 1536];
    float cn = sigmoidf_(gf) * c[idx] + sigmoidf_(gi) * tanhf(gg);
    float hn = sigmoidf_(go) * tanhf(cn);
    hstore[((size_t)(t - 1) * B_ + b) * DD + d] = f2bf(hn);
    bool act = dlen[b] > (t - 1);
    float hv = act ? hn : h[idx];
    float cv = act ? cn : c[idx];
    h[idx] = hv; c[idx] = cv;
    h_bf[idx] = f2bf(hv);
}

// ---------------------------------------------------------------------------
// converts
// ---------------------------------------------------------------------------
__global__ void conv_bf16_kernel(const float* __restrict__ src, unsigned short* __restrict__ dst, int n4)
{
    for (int i = blockIdx.x * 256 + threadIdx.x; i < n4; i += gridDim.x * 256) {
        float4 v = ((const float4*)src)[i];
        ushort4 o;
        o.x = f2bf(v.x); o.y = f2bf(v.y); o.z = f2bf(v.z); o.w = f2bf(v.w);
        ((ushort4*)dst)[i] = o;
    }
}
__global__ void conv_wproj_kernel(const float* __restrict__ dec_W, const float* __restrict__ fbeta_W,
                                  unsigned short* __restrict__ dst)
{   // grid (2, 2560)
    int k = blockIdx.x * 256 + threadIdx.x, n = blockIdx.y;
    float v = (n < AA) ? dec_W[(size_t)n * DD + k] : fbeta_W[(size_t)(n - AA) * DD + k];
    dst[(size_t)n * DD + k] = f2bf(v);
}
__global__ void conv_wcat_kernel(const float* __restrict__ Wih, const float* __restrict__ Whh,
                                 unsigned short* __restrict__ dst)
{   // grid (12, 2048)
    int k = blockIdx.x * 256 + threadIdx.x, n = blockIdx.y;
    float v = (k < 2560) ? Wih[(size_t)n * 2560 + k] : Whh[(size_t)n * DD + (k - 2560)];
    dst[(size_t)n * XKK + k] = f2bf(v);
}
__global__ void conv_fcw_kernel(const float* __restrict__ fc_W, unsigned short* __restrict__ dst)
{   // grid (2, 10048)
    int k = blockIdx.x * 256 + threadIdx.x, n = blockIdx.y;
    float v = (n < VV) ? fc_W[(size_t)n * DD + k] : 0.f;
    dst[(size_t)n * DD + k] = f2bf(v);
}

// ---------------------------------------------------------------------------
extern "C" void kernel_launch(void* const* d_in, const int* in_sizes, int n_in,
                              void* d_out, int out_size, void* d_ws, size_t ws_size,
                              hipStream_t stream)
{
    const float* encoder_out = (const float*)d_in[0];
    const int*   enc_cap     = (const int*)d_in[1];
    const int*   cap_len     = (const int*)d_in[2];
    const float* emb_W       = (const float*)d_in[3];
    const float* init_h_W    = (const float*)d_in[4];
    const float* init_h_b    = (const float*)d_in[5];
    const float* init_c_W    = (const float*)d_in[6];
    const float* init_c_b    = (const float*)d_in[7];
    const float* enc_attn_W  = (const float*)d_in[8];
    const float* enc_attn_b  = (const float*)d_in[9];
    const float* dec_attn_W  = (const float*)d_in[10];
    const float* dec_attn_b  = (const float*)d_in[11];
    const float* full_attn_W = (const float*)d_in[12];
    const float* full_attn_b = (const float*)d_in[13];
    const float* lstm_Wih    = (const float*)d_in[14];
    const float* lstm_Whh    = (const float*)d_in[15];
    const float* lstm_bih    = (const float*)d_in[16];
    const float* lstm_bhh    = (const float*)d_in[17];
    const float* fbeta_W     = (const float*)d_in[18];
    const float* fbeta_b     = (const float*)d_in[19];
    const float* fc_W        = (const float*)d_in[20];
    const float* fc_b        = (const float*)d_in[21];

    char* wsb = (char*)d_ws;
    int*   si     = (int*)(wsb + WS_SI);
    int*   dlen   = (int*)(wsb + WS_DLEN);
    float* battn  = (float*)(wsb + WS_BATTN);
    float* blstm  = (float*)(wsb + WS_BLSTM);
    float* means  = (float*)(wsb + WS_MEANS);
    float* h      = (float*)(wsb + WS_H);
    float* c      = (float*)(wsb + WS_C);
    unsigned short* h_bf   = (unsigned short*)(wsb + WS_HBF);
    float* proj   = (float*)(wsb + WS_PROJ);
    float* alpha  = (float*)(wsb + WS_ALPHA);
    unsigned short* xcat   = (unsigned short*)(wsb + WS_XCAT);
    float* gates  = (float*)(wsb + WS_GATES);
    unsigned short* hstore = (unsigned short*)(wsb + WS_HSTORE);
    unsigned short* wproj  = (unsigned short*)(wsb + WS_WPROJ);
    unsigned short* wcat   = (unsigned short*)(wsb + WS_WCAT);
    unsigned short* fcw    = (unsigned short*)(wsb + WS_FCW);
    unsigned short* efeat  = (unsigned short*)(wsb + WS_EFEAT);
    unsigned short* encbf  = (unsigned short*)(wsb + WS_ENCBF);

    float* out      = (float*)d_out;
    float* out0     = out + OUT0_OFF;
    float* out_caps = out + OUT1_OFF;
    float* out_dlen = out + OUT2_OFF;
    float* alphas   = out + OUT3_OFF;
    float* out_sind = out + OUT4_OFF;

    const int use_encbf = (ws_size >= NEED_ENCBF) ? 1 : 0;

    // ---- setup ----
    sort_kernel<<<1, B_, 0, stream>>>(cap_len, enc_cap, si, dlen, out_caps, out_dlen, out_sind);
    bias_cat_kernel<<<10, 256, 0, stream>>>(dec_attn_b, fbeta_b, lstm_bih, lstm_bhh, battn, blstm);
    enc_mean_sorted<<<(B_ * ENCD) / 256, 256, 0, stream>>>(encoder_out, si, means);

    gemm_nt<<<dim3(DD / BN, 1, 1), 256, 0, stream>>>(means, ENCD, init_h_W, ENCD, init_h_b, h, DD, DD, ENCD);
    gemm_nt<<<dim3(DD / BN, 1, 1), 256, 0, stream>>>(means, ENCD, init_c_W, ENCD, init_c_b, c, DD, DD, ENCD);
    conv_bf16_kernel<<<64, 256, 0, stream>>>(h, h_bf, (B_ * DD) / 4);

    conv_wproj_kernel<<<dim3(2, PROJN), 256, 0, stream>>>(dec_attn_W, fbeta_W, wproj);
    conv_wcat_kernel<<<dim3(12, 2048), 256, 0, stream>>>(lstm_Wih, lstm_Whh, wcat);
    conv_fcw_kernel<<<dim3(2, VPAD), 256, 0, stream>>>(fc_W, fcw);
    if (use_encbf)
        conv_bf16_kernel<<<2048, 256, 0, stream>>>(encoder_out, encbf, (B_ * P_ * ENCD) / 4);

    // enc_feat (unsorted) -> efeat_bf : A,W f32 converted in-kernel
    mfma_gemm<1, true><<<dim3(AA / 64, (B_ * P_) / 128), 256, 0, stream>>>(
        encoder_out, enc_attn_W, enc_attn_b, nullptr, nullptr, efeat, ENCD, AA, AA);

    // ---- decode loop ----
    for (int t = 0; t < TT; ++t) {
        if (t > 0)
            pointwise_kernel<<<(B_ * DD) / 256, 256, 0, stream>>>(gates, dlen, h, c, h_bf, hstore, t);

        // proj = h_bf @ [dec_attn|fbeta]^T + battn
        mfma_gemm<0, false><<<dim3(PROJN / 64, 1), 256, 0, stream>>>(
            h_bf, wproj, battn, nullptr, proj, nullptr, DD, PROJN, PROJN);

        scores_kernel<<<B_, 256, 0, stream>>>(
            efeat, proj, full_attn_W, full_attn_b, si, dlen, enc_cap, emb_W, h_bf,
            alpha, alphas, xcat, t);

        ctx_kernel<<<dim3(4, B_), 256, 0, stream>>>(
            encoder_out, encbf, use_encbf, alpha, proj, si, xcat);

        // gates = x_cat @ [Wih|Whh]^T + blstm
        mfma_gemm<0, false><<<dim3(2048 / 64, 1), 256, 0, stream>>>(
            xcat, wcat, blstm, nullptr, gates, nullptr, XKK, 2048, 2048);
    }
    pointwise_kernel<<<(B_ * DD) / 256, 256, 0, stream>>>(gates, dlen, h, c, h_bf, hstore, TT);

    // fc over all steps: out[b,t,:] = (hstore[t,b,:] @ fc_W^T + fc_b) * (dlen[b] > t)
    mfma_gemm<2, false><<<dim3(VPAD / 64, TT), 256, 0, stream>>>(
        hstore, fcw, fc_b, dlen, out0, nullptr, DD, VV, VV);
}

// Round 3
// 4588.942 us; speedup vs baseline: 2.9485x; 1.3865x over previous
//
#include <hip/hip_runtime.h>
#include <hip/hip_bf16.h>

// Problem dims
#define B_    128
#define P_    196
#define ENCD  2048
#define LL    50
#define VV    10000
#define AA    512
#define DD    512
#define EE    512
#define TT    49
#define XKK   3072    // E + ENC + D
#define PROJN 2560    // A + ENC
#define VPAD  10048   // V rounded up to 64

// Output layout (float offsets)
#define OUT0_OFF 0
#define OUT1_OFF 62720000
#define OUT2_OFF 62726400
#define OUT3_OFF 62726528
#define OUT4_OFF 63955840

// Workspace layout (BYTE offsets)
#define WS_SI      0ull
#define WS_DLEN    512ull
#define WS_BATTN   1024ull
#define WS_BLSTM   11264ull
#define WS_MEANS   19456ull
#define WS_H       1068032ull
#define WS_C       1330176ull
#define WS_HBF     1592320ull
#define WS_PROJ    1723392ull     // 2 slabs x [128][2560] f32
#define WS_XCAT    4344832ull     // [128][3072] bf16
#define WS_GATES   5131264ull     // 4 slabs x [128][2048] f32
#define WS_HSTORE  9325568ull     // [49*128][512] bf16
#define WS_WPROJ   15748096ull    // [2560][512] bf16
#define WS_WCAT    18369536ull    // [2048][3072] bf16
#define WS_FCW     30952448ull    // [10048][512] bf16
#define WS_WENC    41241600ull    // [512][2048] bf16
#define WS_EFEAT   43338752ull    // [25088][512] bf16
#define WS_ENCBF   69028864ull    // [128*196][2048] bf16
#define NEED_ENCBF 171789312ull

typedef __attribute__((ext_vector_type(4))) float f32x4;
typedef __attribute__((ext_vector_type(8))) short s16x8;

__device__ __forceinline__ float sigmoidf_(float x) { return 1.0f / (1.0f + __expf(-x)); }

__device__ __forceinline__ unsigned short f2bf(float x) {
    union { float f; unsigned int u; } v; v.f = x;
    unsigned int r = (v.u + 0x7FFFu + ((v.u >> 16) & 1u)) >> 16;
    return (unsigned short)r;
}
__device__ __forceinline__ float bf2f(unsigned short u) {
    return __uint_as_float(((unsigned int)u) << 16);
}

__device__ __forceinline__ void gload_lds16(const void* g, void* l) {
    __builtin_amdgcn_global_load_lds((const __attribute__((address_space(1))) void*)g,
                                     (__attribute__((address_space(3))) void*)l, 16, 0, 0);
}

// ---------------------------------------------------------------------------
// Stable descending argsort of cap_len (B=128), plus int-ish outputs
// ---------------------------------------------------------------------------
__global__ void sort_kernel(const int* __restrict__ cap_len, const int* __restrict__ enc_cap,
                            int* __restrict__ si, int* __restrict__ dlen,
                            float* __restrict__ out_caps, float* __restrict__ out_dlen,
                            float* __restrict__ out_sind)
{
    __shared__ int cl[B_];
    __shared__ int rank_to_idx[B_];
    int i = threadIdx.x;
    cl[i] = cap_len[i];
    __syncthreads();
    int my = cl[i];
    int r = 0;
    for (int j = 0; j < B_; ++j) {
        int oj = cl[j];
        if (oj > my || (oj == my && j < i)) ++r;
    }
    rank_to_idx[r] = i;
    __syncthreads();
    int src = rank_to_idx[i];
    si[i] = src;
    int dl = cl[src] - 1;
    dlen[i] = dl;
    out_dlen[i] = (float)dl;
    out_sind[i] = (float)src;
    for (int k = 0; k < LL; ++k) out_caps[i * LL + k] = (float)enc_cap[src * LL + k];
}

__global__ void bias_cat_kernel(const float* __restrict__ dec_b, const float* __restrict__ fbeta_b,
                                const float* __restrict__ bih, const float* __restrict__ bhh,
                                float* __restrict__ b_attn, float* __restrict__ b_lstm)
{
    int i = blockIdx.x * 256 + threadIdx.x;
    if (i < AA) b_attn[i] = dec_b[i];
    else if (i < PROJN) b_attn[i] = fbeta_b[i - AA];
    if (i < 2048) b_lstm[i] = bih[i] + bhh[i];
}

// means[b] = mean over P of enc[si[b]]
__global__ void enc_mean_sorted(const float* __restrict__ enc, const int* __restrict__ si,
                                float* __restrict__ means)
{
    int idx = blockIdx.x * 256 + threadIdx.x;   // B*ENC
    int b = idx >> 11, e = idx & 2047;
    const float* p = enc + (size_t)si[b] * P_ * ENCD + e;
    float s = 0.f;
    for (int q = 0; q < P_; ++q) s += p[(size_t)q * ENCD];
    means[idx] = s * (1.0f / 196.0f);
}

// ---------------------------------------------------------------------------
// bf16 MFMA GEMM, double-buffered LDS, one barrier per k-iter.
// C[M,N] = A[M,K] @ W[N,K]^T (+ bias when z==0 && bias!=null)
// BM=128, BN=64, BK=32; 4 waves; wave w owns n-slice w*16..+15, full 128 m.
// Split-K via blockIdx.z: k-range [z*KC, (z+1)*KC), output slab z.
// MODE 0: f32 out; MODE 1: bf16 out;
// MODE 2: fc epilogue — m=(t*128+b), out[(b*49+t)*10000+n] masked by dlen[b]>t, n<Nreal.
// CONV: A and W are f32 sources, converted during reg-staging.
// ---------------------------------------------------------------------------
template<int MODE, bool CONV>
__launch_bounds__(256)
__global__ void mfma_gemm(const void* __restrict__ Av, const void* __restrict__ Wv,
                          const float* __restrict__ bias, const int* __restrict__ dlen,
                          float* __restrict__ Cf, unsigned short* __restrict__ Cbf,
                          int K, int KC, long long ldc, long long slabStride, int Nreal)
{
    __shared__ __align__(16) unsigned short As[2][128 * 32];
    __shared__ __align__(16) unsigned short Ws[2][64 * 32];
    const int tid  = threadIdx.x;
    const int wave = tid >> 6, lane = tid & 63;
    const int m0 = blockIdx.y * 128;
    const int n0 = blockIdx.x * 64;
    const int z  = blockIdx.z;
    const int kbeg = z * KC;
    const int nt = KC / 32;
    const int r16 = lane & 15, kg = lane >> 4;

    f32x4 acc[8];
    #pragma unroll
    for (int i = 0; i < 8; ++i) acc[i] = f32x4{0.f, 0.f, 0.f, 0.f};

    // fast-path staging geometry
    const int a_off0 = wave * 2048 + lane * 16;
    const int a_row0 = a_off0 >> 6, a_c0 = (a_off0 >> 4) & 3;
    const int a_off1 = a_off0 + 1024;
    const int a_row1 = a_off1 >> 6, a_c1 = (a_off1 >> 4) & 3;
    const int w_off  = wave * 1024 + lane * 16;
    const int w_row  = w_off >> 6,  w_c  = (w_off >> 4) & 3;
    // CONV staging geometry
    const int c_arow = tid >> 1, c_acb = (tid & 1) * 16;
    const int c_wrow = tid >> 2, c_wcb = (tid & 3) * 8;

    int buf = 0;

    if constexpr (!CONV) {
        const unsigned short* A = (const unsigned short*)Av;
        const unsigned short* W = (const unsigned short*)Wv;
        // prologue stage into buf 0
        gload_lds16(A + (size_t)(m0 + a_row0) * K + kbeg + a_c0 * 8, &As[0][wave * 1024]);
        gload_lds16(A + (size_t)(m0 + a_row1) * K + kbeg + a_c1 * 8, &As[0][wave * 1024 + 512]);
        gload_lds16(W + (size_t)(n0 + w_row)  * K + kbeg + w_c  * 8, &Ws[0][wave * 512]);
        __syncthreads();
        for (int it = 0; it < nt; ++it) {
            if (it + 1 < nt) {
                int k1 = kbeg + (it + 1) * 32;
                gload_lds16(A + (size_t)(m0 + a_row0) * K + k1 + a_c0 * 8, &As[buf ^ 1][wave * 1024]);
                gload_lds16(A + (size_t)(m0 + a_row1) * K + k1 + a_c1 * 8, &As[buf ^ 1][wave * 1024 + 512]);
                gload_lds16(W + (size_t)(n0 + w_row)  * K + k1 + w_c  * 8, &Ws[buf ^ 1][wave * 512]);
            }
            s16x8 bfrag = *(const s16x8*)&Ws[buf][(wave * 16 + r16) * 32 + kg * 8];
            #pragma unroll
            for (int i = 0; i < 8; ++i) {
                s16x8 afrag = *(const s16x8*)&As[buf][(i * 16 + r16) * 32 + kg * 8];
                acc[i] = __builtin_amdgcn_mfma_f32_16x16x32_bf16(afrag, bfrag, acc[i], 0, 0, 0);
            }
            __syncthreads();
            buf ^= 1;
        }
    } else {
        const float* A = (const float*)Av;
        const float* W = (const float*)Wv;
        float ra[16], rw[8];
        #pragma unroll
        for (int j = 0; j < 16; ++j) ra[j] = A[(size_t)(m0 + c_arow) * K + kbeg + c_acb + j];
        #pragma unroll
        for (int j = 0; j < 8; ++j)  rw[j] = W[(size_t)(n0 + c_wrow) * K + kbeg + c_wcb + j];
        {
            unsigned short t0[16], t1[8];
            #pragma unroll
            for (int j = 0; j < 16; ++j) t0[j] = f2bf(ra[j]);
            #pragma unroll
            for (int j = 0; j < 8; ++j)  t1[j] = f2bf(rw[j]);
            *(s16x8*)&As[0][c_arow * 32 + c_acb]     = *(s16x8*)&t0[0];
            *(s16x8*)&As[0][c_arow * 32 + c_acb + 8] = *(s16x8*)&t0[8];
            *(s16x8*)&Ws[0][c_wrow * 32 + c_wcb]     = *(s16x8*)&t1[0];
        }
        __syncthreads();
        for (int it = 0; it < nt; ++it) {
            float ra2[16], rw2[8];
            bool more = (it + 1 < nt);
            if (more) {
                int k1 = kbeg + (it + 1) * 32;
                #pragma unroll
                for (int j = 0; j < 16; ++j) ra2[j] = A[(size_t)(m0 + c_arow) * K + k1 + c_acb + j];
                #pragma unroll
                for (int j = 0; j < 8; ++j)  rw2[j] = W[(size_t)(n0 + c_wrow) * K + k1 + c_wcb + j];
            }
            s16x8 bfrag = *(const s16x8*)&Ws[buf][(wave * 16 + r16) * 32 + kg * 8];
            #pragma unroll
            for (int i = 0; i < 8; ++i) {
                s16x8 afrag = *(const s16x8*)&As[buf][(i * 16 + r16) * 32 + kg * 8];
                acc[i] = __builtin_amdgcn_mfma_f32_16x16x32_bf16(afrag, bfrag, acc[i], 0, 0, 0);
            }
            if (more) {
                unsigned short t0[16], t1[8];
                #pragma unroll
                for (int j = 0; j < 16; ++j) t0[j] = f2bf(ra2[j]);
                #pragma unroll
                for (int j = 0; j < 8; ++j)  t1[j] = f2bf(rw2[j]);
                *(s16x8*)&As[buf ^ 1][c_arow * 32 + c_acb]     = *(s16x8*)&t0[0];
                *(s16x8*)&As[buf ^ 1][c_arow * 32 + c_acb + 8] = *(s16x8*)&t0[8];
                *(s16x8*)&Ws[buf ^ 1][c_wrow * 32 + c_wcb]     = *(s16x8*)&t1[0];
            }
            __syncthreads();
            buf ^= 1;
        }
    }

    int n = n0 + wave * 16 + r16;
    float bv = 0.f;
    if (bias && z == 0) bv = (MODE == 2) ? (n < Nreal ? bias[n] : 0.f) : bias[n];
    float* Cz = Cf + (size_t)z * slabStride;
    #pragma unroll
    for (int i = 0; i < 8; ++i) {
        #pragma unroll
        for (int r = 0; r < 4; ++r) {
            int m = m0 + i * 16 + kg * 4 + r;
            float v = acc[i][r] + bv;
            if (MODE == 0) {
                Cz[(size_t)m * ldc + n] = v;
            } else if (MODE == 1) {
                Cbf[(size_t)m * ldc + n] = f2bf(v);
            } else {
                int bb = m & 127, tt2 = m >> 7;
                if (n < Nreal)
                    Cf[((size_t)bb * TT + tt2) * VV + n] = (dlen[bb] > tt2) ? v : 0.f;
            }
        }
    }
}

// ---------------------------------------------------------------------------
// Fused scores + softmax + ctx + x_cat fill. One block per b (128 blocks).
// proj is 2 split-K slabs; df = slab0+slab1+battn.
// Phase A: alpha (softmax over P). Phase B: ctx[e] = sig(gate)*sum_p alpha*enc.
// ---------------------------------------------------------------------------
__global__ void scoresctx_kernel(const unsigned short* __restrict__ efeat,
                                 const float* __restrict__ proj, const float* __restrict__ battn,
                                 const float* __restrict__ full_W, const float* __restrict__ full_b,
                                 const int* __restrict__ si, const int* __restrict__ dlen,
                                 const int* __restrict__ enc_cap, const float* __restrict__ emb_W,
                                 const unsigned short* __restrict__ h_bf,
                                 const float* __restrict__ encf, const unsigned short* __restrict__ encbf,
                                 int use_bf,
                                 float* __restrict__ alphas_out, unsigned short* __restrict__ xcat, int t)
{
    int b = blockIdx.x, tid = threadIdx.x;
    int wave = tid >> 6, lane = tid & 63;
    __shared__ float df[AA];
    __shared__ float wf[AA];
    __shared__ float sc[P_];
    __shared__ float red[8];
    int sb = si[b];
    const float* p0 = proj + (size_t)b * PROJN;
    const float* p1 = proj + (size_t)B_ * PROJN + (size_t)b * PROJN;
    for (int i = tid; i < AA; i += 256) { df[i] = p0[i] + p1[i] + battn[i]; wf[i] = full_W[i]; }
    __syncthreads();
    const float fb = full_b[0];
    float dfv[8], wfv[8];
    #pragma unroll
    for (int j = 0; j < 8; ++j) { dfv[j] = df[lane * 8 + j]; wfv[j] = wf[lane * 8 + j]; }
    for (int p = wave; p < P_; p += 4) {
        const unsigned short* ef = efeat + ((size_t)sb * P_ + p) * AA + lane * 8;
        s16x8 ev = *(const s16x8*)ef;
        float s = 0.f;
        #pragma unroll
        for (int j = 0; j < 8; ++j) {
            float e = bf2f((unsigned short)ev[j]);
            float v = e + dfv[j];
            v = v > 0.f ? v : 0.f;
            s += v * wfv[j];
        }
        #pragma unroll
        for (int off = 32; off; off >>= 1) s += __shfl_down(s, off);
        if (lane == 0) sc[p] = s + fb;
    }
    __syncthreads();
    float m = -1e30f;
    for (int p = tid; p < P_; p += 256) m = fmaxf(m, sc[p]);
    for (int off = 32; off; off >>= 1) m = fmaxf(m, __shfl_down(m, off));
    if (lane == 0) red[wave] = m;
    __syncthreads();
    if (tid == 0) {
        float mm = red[0];
        for (int w = 1; w < 4; ++w) mm = fmaxf(mm, red[w]);
        red[4] = mm;
    }
    __syncthreads();
    m = red[4];
    float ssum = 0.f;
    for (int p = tid; p < P_; p += 256) { float e = __expf(sc[p] - m); sc[p] = e; ssum += e; }
    for (int off = 32; off; off >>= 1) ssum += __shfl_down(ssum, off);
    if (lane == 0) red[wave] = ssum;
    __syncthreads();
    if (tid == 0) {
        float s2 = 0.f;
        for (int w = 0; w < 4; ++w) s2 += red[w];
        red[5] = 1.0f / s2;
    }
    __syncthreads();
    float inv = red[5];
    float af = (dlen[b] > t) ? 1.0f : 0.0f;
    for (int p = tid; p < P_; p += 256) {
        float a = sc[p] * inv;
        alphas_out[((size_t)b * TT + t) * P_ + p] = a * af;
        sc[p] = a;                                  // normalized alpha for phase B
    }
    // x_cat emb + h fill
    int tok = enc_cap[sb * LL + t];
    for (int k = tid; k < EE; k += 256) {
        xcat[(size_t)b * XKK + k]        = f2bf(emb_W[(size_t)tok * EE + k]);
        xcat[(size_t)b * XKK + 2560 + k] = h_bf[b * DD + k];
    }
    __syncthreads();

    // ---- phase B: ctx. wave w owns e-range [w*512, (w+1)*512), 8 e per lane ----
    int e0 = wave * 512 + lane * 8;
    float acc[8] = {};
    if (use_bf) {
        const unsigned short* base = encbf + (size_t)sb * P_ * ENCD + e0;
        #pragma unroll 4
        for (int p = 0; p < P_; ++p) {
            s16x8 u = *(const s16x8*)(base + (size_t)p * ENCD);
            float al = sc[p];
            #pragma unroll
            for (int j = 0; j < 8; ++j) acc[j] = fmaf(al, bf2f((unsigned short)u[j]), acc[j]);
        }
    } else {
        const float* base = encf + (size_t)sb * P_ * ENCD + e0;
        #pragma unroll 4
        for (int p = 0; p < P_; ++p) {
            float4 u0 = *(const float4*)(base + (size_t)p * ENCD);
            float4 u1 = *(const float4*)(base + (size_t)p * ENCD + 4);
            float al = sc[p];
            acc[0] = fmaf(al, u0.x, acc[0]); acc[1] = fmaf(al, u0.y, acc[1]);
            acc[2] = fmaf(al, u0.z, acc[2]); acc[3] = fmaf(al, u0.w, acc[3]);
            acc[4] = fmaf(al, u1.x, acc[4]); acc[5] = fmaf(al, u1.y, acc[5]);
            acc[6] = fmaf(al, u1.z, acc[6]); acc[7] = fmaf(al, u1.w, acc[7]);
        }
    }
    const float* g0 = p0 + AA + e0;
    const float* g1 = p1 + AA + e0;
    const float* bb = battn + AA + e0;
    unsigned short xc[8];
    #pragma unroll
    for (int j = 0; j < 8; ++j) {
        float g = sigmoidf_(g0[j] + g1[j] + bb[j]);
        xc[j] = f2bf(acc[j] * g);
    }
    *(s16x8*)&xcat[(size_t)b * XKK + EE + e0] = *(s16x8*)&xc[0];
}

// ---------------------------------------------------------------------------
// LSTM pointwise for step (t-1): sum 4 gate slabs + bias -> h,c update
// ---------------------------------------------------------------------------
__global__ void pointwise_kernel(const float* __restrict__ gates, const float* __restrict__ blstm,
                                 const int* __restrict__ dlen,
                                 float* __restrict__ h, float* __restrict__ c,
                                 unsigned short* __restrict__ h_bf, unsigned short* __restrict__ hstore,
                                 int t)
{
    int idx = blockIdx.x * 256 + threadIdx.x;   // B*D
    int b = idx >> 9, d = idx & 511;
    const size_t slab = (size_t)B_ * 2048;
    const float* g = gates + (size_t)b * 2048;
    float gi = blstm[d], gf = blstm[512 + d], gg = blstm[1024 + d], go = blstm[1536 + d];
    #pragma unroll
    for (int z = 0; z < 4; ++z) {
        gi += g[z * slab + d];
        gf += g[z * slab + 512 + d];
        gg += g[z * slab + 1024 + d];
        go += g[z * slab + 1536 + d];
    }
    float cn = sigmoidf_(gf) * c[idx] + sigmoidf_(gi) * tanhf(gg);
    float hn = sigmoidf_(go) * tanhf(cn);
    hstore[((size_t)(t - 1) * B_ + b) * DD + d] = f2bf(hn);
    bool act = dlen[b] > (t - 1);
    float hv = act ? hn : h[idx];
    float cv = act ? cn : c[idx];
    h[idx] = hv; c[idx] = cv;
    h_bf[idx] = f2bf(hv);
}

// ---------------------------------------------------------------------------
// converts
// ---------------------------------------------------------------------------
__global__ void conv_bf16_kernel(const float* __restrict__ src, unsigned short* __restrict__ dst, int n4)
{
    for (int i = blockIdx.x * 256 + threadIdx.x; i < n4; i += gridDim.x * 256) {
        float4 v = ((const float4*)src)[i];
        ushort4 o;
        o.x = f2bf(v.x); o.y = f2bf(v.y); o.z = f2bf(v.z); o.w = f2bf(v.w);
        ((ushort4*)dst)[i] = o;
    }
}
__global__ void conv_wproj_kernel(const float* __restrict__ dec_W, const float* __restrict__ fbeta_W,
                                  unsigned short* __restrict__ dst)
{   // grid (2, 2560)
    int k = blockIdx.x * 256 + threadIdx.x, n = blockIdx.y;
    float v = (n < AA) ? dec_W[(size_t)n * DD + k] : fbeta_W[(size_t)(n - AA) * DD + k];
    dst[(size_t)n * DD + k] = f2bf(v);
}
__global__ void conv_wcat_kernel(const float* __restrict__ Wih, const float* __restrict__ Whh,
                                 unsigned short* __restrict__ dst)
{   // grid (12, 2048)
    int k = blockIdx.x * 256 + threadIdx.x, n = blockIdx.y;
    float v = (k < 2560) ? Wih[(size_t)n * 2560 + k] : Whh[(size_t)n * DD + (k - 2560)];
    dst[(size_t)n * XKK + k] = f2bf(v);
}
__global__ void conv_fcw_kernel(const float* __restrict__ fc_W, unsigned short* __restrict__ dst)
{   // grid (2, 10048)
    int k = blockIdx.x * 256 + threadIdx.x, n = blockIdx.y;
    float v = (n < VV) ? fc_W[(size_t)n * DD + k] : 0.f;
    dst[(size_t)n * DD + k] = f2bf(v);
}

// ---------------------------------------------------------------------------
extern "C" void kernel_launch(void* const* d_in, const int* in_sizes, int n_in,
                              void* d_out, int out_size, void* d_ws, size_t ws_size,
                              hipStream_t stream)
{
    const float* encoder_out = (const float*)d_in[0];
    const int*   enc_cap     = (const int*)d_in[1];
    const int*   cap_len     = (const int*)d_in[2];
    const float* emb_W       = (const float*)d_in[3];
    const float* init_h_W    = (const float*)d_in[4];
    const float* init_h_b    = (const float*)d_in[5];
    const float* init_c_W    = (const float*)d_in[6];
    const float* init_c_b    = (const float*)d_in[7];
    const float* enc_attn_W  = (const float*)d_in[8];
    const float* enc_attn_b  = (const float*)d_in[9];
    const float* dec_attn_W  = (const float*)d_in[10];
    const float* dec_attn_b  = (const float*)d_in[11];
    const float* full_attn_W = (const float*)d_in[12];
    const float* full_attn_b = (const float*)d_in[13];
    const float* lstm_Wih    = (const float*)d_in[14];
    const float* lstm_Whh    = (const float*)d_in[15];
    const float* lstm_bih    = (const float*)d_in[16];
    const float* lstm_bhh    = (const float*)d_in[17];
    const float* fbeta_W     = (const float*)d_in[18];
    const float* fbeta_b     = (const float*)d_in[19];
    const float* fc_W        = (const float*)d_in[20];
    const float* fc_b        = (const float*)d_in[21];

    char* wsb = (char*)d_ws;
    int*   si     = (int*)(wsb + WS_SI);
    int*   dlen   = (int*)(wsb + WS_DLEN);
    float* battn  = (float*)(wsb + WS_BATTN);
    float* blstm  = (float*)(wsb + WS_BLSTM);
    float* means  = (float*)(wsb + WS_MEANS);
    float* h      = (float*)(wsb + WS_H);
    float* c      = (float*)(wsb + WS_C);
    unsigned short* h_bf   = (unsigned short*)(wsb + WS_HBF);
    float* proj   = (float*)(wsb + WS_PROJ);
    unsigned short* xcat   = (unsigned short*)(wsb + WS_XCAT);
    float* gates  = (float*)(wsb + WS_GATES);
    unsigned short* hstore = (unsigned short*)(wsb + WS_HSTORE);
    unsigned short* wproj  = (unsigned short*)(wsb + WS_WPROJ);
    unsigned short* wcat   = (unsigned short*)(wsb + WS_WCAT);
    unsigned short* fcw    = (unsigned short*)(wsb + WS_FCW);
    unsigned short* wenc   = (unsigned short*)(wsb + WS_WENC);
    unsigned short* efeat  = (unsigned short*)(wsb + WS_EFEAT);
    unsigned short* encbf  = (unsigned short*)(wsb + WS_ENCBF);

    float* out      = (float*)d_out;
    float* out0     = out + OUT0_OFF;
    float* out_caps = out + OUT1_OFF;
    float* out_dlen = out + OUT2_OFF;
    float* alphas   = out + OUT3_OFF;
    float* out_sind = out + OUT4_OFF;

    const int use_encbf = (ws_size >= NEED_ENCBF) ? 1 : 0;

    // ---- setup ----
    sort_kernel<<<1, B_, 0, stream>>>(cap_len, enc_cap, si, dlen, out_caps, out_dlen, out_sind);
    bias_cat_kernel<<<10, 256, 0, stream>>>(dec_attn_b, fbeta_b, lstm_bih, lstm_bhh, battn, blstm);
    enc_mean_sorted<<<(B_ * ENCD) / 256, 256, 0, stream>>>(encoder_out, si, means);

    // h0/c0 via MFMA CONV path (f32 in, f32 out), K=2048
    mfma_gemm<0, true><<<dim3(DD / 64, 1, 1), 256, 0, stream>>>(
        means, init_h_W, init_h_b, nullptr, h, nullptr, ENCD, ENCD, DD, 0, DD);
    mfma_gemm<0, true><<<dim3(DD / 64, 1, 1), 256, 0, stream>>>(
        means, init_c_W, init_c_b, nullptr, c, nullptr, ENCD, ENCD, DD, 0, DD);
    conv_bf16_kernel<<<64, 256, 0, stream>>>(h, h_bf, (B_ * DD) / 4);

    conv_wproj_kernel<<<dim3(2, PROJN), 256, 0, stream>>>(dec_attn_W, fbeta_W, wproj);
    conv_wcat_kernel<<<dim3(12, 2048), 256, 0, stream>>>(lstm_Wih, lstm_Whh, wcat);
    conv_fcw_kernel<<<dim3(2, VPAD), 256, 0, stream>>>(fc_W, fcw);
    conv_bf16_kernel<<<256, 256, 0, stream>>>(enc_attn_W, wenc, (AA * ENCD) / 4);
    if (use_encbf)
        conv_bf16_kernel<<<2048, 256, 0, stream>>>(encoder_out, encbf, (B_ * P_ * ENCD) / 4);

    // enc_feat -> efeat bf16
    if (use_encbf)
        mfma_gemm<1, false><<<dim3(AA / 64, (B_ * P_) / 128, 1), 256, 0, stream>>>(
            encbf, wenc, enc_attn_b, nullptr, nullptr, efeat, ENCD, ENCD, AA, 0, AA);
    else
        mfma_gemm<1, true><<<dim3(AA / 64, (B_ * P_) / 128, 1), 256, 0, stream>>>(
            encoder_out, enc_attn_W, enc_attn_b, nullptr, nullptr, efeat, ENCD, ENCD, AA, 0, AA);

    // ---- decode loop ----
    for (int t = 0; t < TT; ++t) {
        if (t > 0)
            pointwise_kernel<<<(B_ * DD) / 256, 256, 0, stream>>>(gates, blstm, dlen, h, c, h_bf, hstore, t);

        // proj = h_bf @ [dec_attn|fbeta]^T : split-K x2 slabs (bias in consumer)
        mfma_gemm<0, false><<<dim3(PROJN / 64, 1, 2), 256, 0, stream>>>(
            h_bf, wproj, nullptr, nullptr, proj, nullptr, DD, 256, PROJN, (long long)B_ * PROJN, PROJN);

        scoresctx_kernel<<<B_, 256, 0, stream>>>(
            efeat, proj, battn, full_attn_W, full_attn_b, si, dlen, enc_cap, emb_W, h_bf,
            encoder_out, encbf, use_encbf, alphas, xcat, t);

        // gates = x_cat @ [Wih|Whh]^T : split-K x4 slabs (bias in pointwise)
        mfma_gemm<0, false><<<dim3(2048 / 64, 1, 4), 256, 0, stream>>>(
            xcat, wcat, nullptr, nullptr, gates, nullptr, XKK, 768, 2048, (long long)B_ * 2048, 2048);
    }
    pointwise_kernel<<<(B_ * DD) / 256, 256, 0, stream>>>(gates, blstm, dlen, h, c, h_bf, hstore, TT);

    // fc over all steps: out[b,t,:] = (hstore[t,b,:] @ fc_W^T + fc_b) * (dlen[b] > t)
    mfma_gemm<2, false><<<dim3(VPAD / 64, TT, 1), 256, 0, stream>>>(
        hstore, fcw, fc_b, dlen, out0, nullptr, DD, DD, VV, 0, VV);
}

// Round 4
// 3676.863 us; speedup vs baseline: 3.6799x; 1.2481x over previous
//
#include <hip/hip_runtime.h>
#include <hip/hip_bf16.h>

// Problem dims
#define B_    128
#define P_    196
#define ENCD  2048
#define LL    50
#define VV    10000
#define AA    512
#define DD    512
#define EE    512
#define TT    49
#define XKK   3072    // E + ENC + D
#define PROJN 2560    // A + ENC
#define VPAD  10048   // V rounded up to 64

// Output layout (float offsets)
#define OUT0_OFF 0
#define OUT1_OFF 62720000
#define OUT2_OFF 62726400
#define OUT3_OFF 62726528
#define OUT4_OFF 63955840

// Workspace layout (BYTE offsets)
#define WS_SI      0ull
#define WS_DLEN    512ull
#define WS_BATTN   1024ull
#define WS_BLSTM   11264ull
#define WS_MEANS   19456ull      // [128][2048] f32 (init only) — reused as sc [128][196] f32 in loop
#define WS_H       1068032ull
#define WS_C       1330176ull
#define WS_HBF     1592320ull
#define WS_PROJ    1723392ull    // 2 slabs x [128][2560] f32
#define WS_XCAT    4344832ull    // [128][3072] bf16
#define WS_GATES   5131264ull    // 4 slabs x [128][2048] f32
#define WS_HSTORE  9325568ull    // [49*128][512] bf16
#define WS_WPROJ   15748096ull   // [2560][512] bf16
#define WS_WCAT    18369536ull   // [2048][3072] bf16
#define WS_FCW     30952448ull   // [10048][512] bf16
#define WS_WENC    41241600ull   // [512][2048] bf16
#define WS_EFEAT   43338752ull   // [25088][512] bf16
#define WS_ENCBF   69028864ull   // [128*196][2048] bf16
#define NEED_ENCBF 171789312ull

typedef __attribute__((ext_vector_type(4))) float f32x4;
typedef __attribute__((ext_vector_type(8))) short s16x8;

__device__ __forceinline__ float sigmoidf_(float x) { return 1.0f / (1.0f + __expf(-x)); }

__device__ __forceinline__ unsigned short f2bf(float x) {
    union { float f; unsigned int u; } v; v.f = x;
    unsigned int r = (v.u + 0x7FFFu + ((v.u >> 16) & 1u)) >> 16;
    return (unsigned short)r;
}
__device__ __forceinline__ float bf2f(unsigned short u) {
    return __uint_as_float(((unsigned int)u) << 16);
}

__device__ __forceinline__ void gload_lds16(const void* g, void* l) {
    __builtin_amdgcn_global_load_lds((const __attribute__((address_space(1))) void*)g,
                                     (__attribute__((address_space(3))) void*)l, 16, 0, 0);
}

// ---------------------------------------------------------------------------
// Stable descending argsort of cap_len (B=128), plus int-ish outputs
// ---------------------------------------------------------------------------
__global__ void sort_kernel(const int* __restrict__ cap_len, const int* __restrict__ enc_cap,
                            int* __restrict__ si, int* __restrict__ dlen,
                            float* __restrict__ out_caps, float* __restrict__ out_dlen,
                            float* __restrict__ out_sind)
{
    __shared__ int cl[B_];
    __shared__ int rank_to_idx[B_];
    int i = threadIdx.x;
    cl[i] = cap_len[i];
    __syncthreads();
    int my = cl[i];
    int r = 0;
    for (int j = 0; j < B_; ++j) {
        int oj = cl[j];
        if (oj > my || (oj == my && j < i)) ++r;
    }
    rank_to_idx[r] = i;
    __syncthreads();
    int src = rank_to_idx[i];
    si[i] = src;
    int dl = cl[src] - 1;
    dlen[i] = dl;
    out_dlen[i] = (float)dl;
    out_sind[i] = (float)src;
    for (int k = 0; k < LL; ++k) out_caps[i * LL + k] = (float)enc_cap[src * LL + k];
}

__global__ void bias_cat_kernel(const float* __restrict__ dec_b, const float* __restrict__ fbeta_b,
                                const float* __restrict__ bih, const float* __restrict__ bhh,
                                float* __restrict__ b_attn, float* __restrict__ b_lstm)
{
    int i = blockIdx.x * 256 + threadIdx.x;
    if (i < AA) b_attn[i] = dec_b[i];
    else if (i < PROJN) b_attn[i] = fbeta_b[i - AA];
    if (i < 2048) b_lstm[i] = bih[i] + bhh[i];
}

// means[b] = mean over P of enc[si[b]]
__global__ void enc_mean_sorted(const float* __restrict__ enc, const int* __restrict__ si,
                                float* __restrict__ means)
{
    int idx = blockIdx.x * 256 + threadIdx.x;   // B*ENC
    int b = idx >> 11, e = idx & 2047;
    const float* p = enc + (size_t)si[b] * P_ * ENCD + e;
    float s = 0.f;
    for (int q = 0; q < P_; ++q) s += p[(size_t)q * ENCD];
    means[idx] = s * (1.0f / 196.0f);
}

// ---------------------------------------------------------------------------
// bf16 MFMA GEMM, double-buffered LDS, one barrier per k-iter.
// C[M,N] = A[M,K] @ W[N,K]^T (+ bias when z==0 && bias!=null)
// BM=128, BN=64, BK=32; 4 waves; wave w owns n-slice w*16..+15, full 128 m.
// Split-K via blockIdx.z: k-range [z*KC, (z+1)*KC), output slab z.
// MODE 0: f32 out; MODE 1: bf16 out;
// MODE 2: fc epilogue — grid (T, N/64): m0 from blockIdx.x, n0 from blockIdx.y;
//         m=(t*128+b), out[(b*49+t)*10000+n] masked by dlen[b]>t, n<Nreal.
// CONV: A and W are f32 sources, converted during reg-staging.
// ---------------------------------------------------------------------------
template<int MODE, bool CONV>
__launch_bounds__(256)
__global__ void mfma_gemm(const void* __restrict__ Av, const void* __restrict__ Wv,
                          const float* __restrict__ bias, const int* __restrict__ dlen,
                          float* __restrict__ Cf, unsigned short* __restrict__ Cbf,
                          int K, int KC, long long ldc, long long slabStride, int Nreal)
{
    __shared__ __align__(16) unsigned short As[2][128 * 32];
    __shared__ __align__(16) unsigned short Ws[2][64 * 32];
    const int tid  = threadIdx.x;
    const int wave = tid >> 6, lane = tid & 63;
    const int m0 = (MODE == 2 ? blockIdx.x : blockIdx.y) * 128;
    const int n0 = (MODE == 2 ? blockIdx.y : blockIdx.x) * 64;
    const int z  = blockIdx.z;
    const int kbeg = z * KC;
    const int nt = KC / 32;
    const int r16 = lane & 15, kg = lane >> 4;

    f32x4 acc[8];
    #pragma unroll
    for (int i = 0; i < 8; ++i) acc[i] = f32x4{0.f, 0.f, 0.f, 0.f};

    // fast-path staging geometry
    const int a_off0 = wave * 2048 + lane * 16;
    const int a_row0 = a_off0 >> 6, a_c0 = (a_off0 >> 4) & 3;
    const int a_off1 = a_off0 + 1024;
    const int a_row1 = a_off1 >> 6, a_c1 = (a_off1 >> 4) & 3;
    const int w_off  = wave * 1024 + lane * 16;
    const int w_row  = w_off >> 6,  w_c  = (w_off >> 4) & 3;
    // CONV staging geometry
    const int c_arow = tid >> 1, c_acb = (tid & 1) * 16;
    const int c_wrow = tid >> 2, c_wcb = (tid & 3) * 8;

    int buf = 0;

    if constexpr (!CONV) {
        const unsigned short* A = (const unsigned short*)Av;
        const unsigned short* W = (const unsigned short*)Wv;
        // prologue stage into buf 0
        gload_lds16(A + (size_t)(m0 + a_row0) * K + kbeg + a_c0 * 8, &As[0][wave * 1024]);
        gload_lds16(A + (size_t)(m0 + a_row1) * K + kbeg + a_c1 * 8, &As[0][wave * 1024 + 512]);
        gload_lds16(W + (size_t)(n0 + w_row)  * K + kbeg + w_c  * 8, &Ws[0][wave * 512]);
        __syncthreads();
        for (int it = 0; it < nt; ++it) {
            if (it + 1 < nt) {
                int k1 = kbeg + (it + 1) * 32;
                gload_lds16(A + (size_t)(m0 + a_row0) * K + k1 + a_c0 * 8, &As[buf ^ 1][wave * 1024]);
                gload_lds16(A + (size_t)(m0 + a_row1) * K + k1 + a_c1 * 8, &As[buf ^ 1][wave * 1024 + 512]);
                gload_lds16(W + (size_t)(n0 + w_row)  * K + k1 + w_c  * 8, &Ws[buf ^ 1][wave * 512]);
            }
            s16x8 bfrag = *(const s16x8*)&Ws[buf][(wave * 16 + r16) * 32 + kg * 8];
            #pragma unroll
            for (int i = 0; i < 8; ++i) {
                s16x8 afrag = *(const s16x8*)&As[buf][(i * 16 + r16) * 32 + kg * 8];
                acc[i] = __builtin_amdgcn_mfma_f32_16x16x32_bf16(afrag, bfrag, acc[i], 0, 0, 0);
            }
            __syncthreads();
            buf ^= 1;
        }
    } else {
        const float* A = (const float*)Av;
        const float* W = (const float*)Wv;
        float ra[16], rw[8];
        #pragma unroll
        for (int j = 0; j < 16; ++j) ra[j] = A[(size_t)(m0 + c_arow) * K + kbeg + c_acb + j];
        #pragma unroll
        for (int j = 0; j < 8; ++j)  rw[j] = W[(size_t)(n0 + c_wrow) * K + kbeg + c_wcb + j];
        {
            unsigned short t0[16], t1[8];
            #pragma unroll
            for (int j = 0; j < 16; ++j) t0[j] = f2bf(ra[j]);
            #pragma unroll
            for (int j = 0; j < 8; ++j)  t1[j] = f2bf(rw[j]);
            *(s16x8*)&As[0][c_arow * 32 + c_acb]     = *(s16x8*)&t0[0];
            *(s16x8*)&As[0][c_arow * 32 + c_acb + 8] = *(s16x8*)&t0[8];
            *(s16x8*)&Ws[0][c_wrow * 32 + c_wcb]     = *(s16x8*)&t1[0];
        }
        __syncthreads();
        for (int it = 0; it < nt; ++it) {
            float ra2[16], rw2[8];
            bool more = (it + 1 < nt);
            if (more) {
                int k1 = kbeg + (it + 1) * 32;
                #pragma unroll
                for (int j = 0; j < 16; ++j) ra2[j] = A[(size_t)(m0 + c_arow) * K + k1 + c_acb + j];
                #pragma unroll
                for (int j = 0; j < 8; ++j)  rw2[j] = W[(size_t)(n0 + c_wrow) * K + k1 + c_wcb + j];
            }
            s16x8 bfrag = *(const s16x8*)&Ws[buf][(wave * 16 + r16) * 32 + kg * 8];
            #pragma unroll
            for (int i = 0; i < 8; ++i) {
                s16x8 afrag = *(const s16x8*)&As[buf][(i * 16 + r16) * 32 + kg * 8];
                acc[i] = __builtin_amdgcn_mfma_f32_16x16x32_bf16(afrag, bfrag, acc[i], 0, 0, 0);
            }
            if (more) {
                unsigned short t0[16], t1[8];
                #pragma unroll
                for (int j = 0; j < 16; ++j) t0[j] = f2bf(ra2[j]);
                #pragma unroll
                for (int j = 0; j < 8; ++j)  t1[j] = f2bf(rw2[j]);
                *(s16x8*)&As[buf ^ 1][c_arow * 32 + c_acb]     = *(s16x8*)&t0[0];
                *(s16x8*)&As[buf ^ 1][c_arow * 32 + c_acb + 8] = *(s16x8*)&t0[8];
                *(s16x8*)&Ws[buf ^ 1][c_wrow * 32 + c_wcb]     = *(s16x8*)&t1[0];
            }
            __syncthreads();
            buf ^= 1;
        }
    }

    int n = n0 + wave * 16 + r16;
    float bv = 0.f;
    if (bias && z == 0) bv = (MODE == 2) ? (n < Nreal ? bias[n] : 0.f) : bias[n];
    float* Cz = Cf + (size_t)z * slabStride;
    #pragma unroll
    for (int i = 0; i < 8; ++i) {
        #pragma unroll
        for (int r = 0; r < 4; ++r) {
            int m = m0 + i * 16 + kg * 4 + r;
            float v = acc[i][r] + bv;
            if (MODE == 0) {
                Cz[(size_t)m * ldc + n] = v;
            } else if (MODE == 1) {
                Cbf[(size_t)m * ldc + n] = f2bf(v);
            } else {
                int bb = m & 127, tt2 = m >> 7;
                if (n < Nreal)
                    Cf[((size_t)bb * TT + tt2) * VV + n] = (dlen[bb] > tt2) ? v : 0.f;
            }
        }
    }
}

// ---------------------------------------------------------------------------
// scores_raw: sc[b][p] = relu(efeat[sb,p,:] + df[b,:]) . full_W + full_b
// grid (128, 4): block (b, quarter); quarter covers 49 p-rows; 4 waves.
// ---------------------------------------------------------------------------
__global__ void scores_raw_kernel(const unsigned short* __restrict__ efeat,
                                  const float* __restrict__ proj, const float* __restrict__ battn,
                                  const float* __restrict__ full_W, const float* __restrict__ full_b,
                                  const int* __restrict__ si,
                                  float* __restrict__ sc_out)
{
    int b = blockIdx.x, q = blockIdx.y;
    int tid = threadIdx.x, wave = tid >> 6, lane = tid & 63;
    __shared__ float df[AA];
    __shared__ float wf[AA];
    const float* p0 = proj + (size_t)b * PROJN;
    const float* p1 = proj + (size_t)B_ * PROJN + (size_t)b * PROJN;
    for (int i = tid; i < AA; i += 256) { df[i] = p0[i] + p1[i] + battn[i]; wf[i] = full_W[i]; }
    __syncthreads();
    int sb = si[b];
    const float fb = full_b[0];
    float dfv[8], wfv[8];
    #pragma unroll
    for (int j = 0; j < 8; ++j) { dfv[j] = df[lane * 8 + j]; wfv[j] = wf[lane * 8 + j]; }
    int pbeg = q * 49;
    for (int p = pbeg + wave; p < pbeg + 49; p += 4) {
        const unsigned short* ef = efeat + ((size_t)sb * P_ + p) * AA + lane * 8;
        s16x8 ev = *(const s16x8*)ef;
        float s = 0.f;
        #pragma unroll
        for (int j = 0; j < 8; ++j) {
            float e = bf2f((unsigned short)ev[j]);
            float v = e + dfv[j];
            v = v > 0.f ? v : 0.f;
            s += v * wfv[j];
        }
        #pragma unroll
        for (int off = 32; off; off >>= 1) s += __shfl_down(s, off);
        if (lane == 0) sc_out[b * P_ + p] = s + fb;
    }
}

// ---------------------------------------------------------------------------
// ctx_fused: recompute softmax from raw scores (cheap, redundant per block),
// accumulate ctx over the block's e-slice, apply gate, write xcat.
// Block x==0 also writes alphas output and the emb/h parts of xcat.
// grid (4, 128), 256 threads; each thread owns 2 consecutive e.
// ---------------------------------------------------------------------------
__global__ void ctx_fused_kernel(const float* __restrict__ sc_in,
                                 const float* __restrict__ proj, const float* __restrict__ battn,
                                 const int* __restrict__ si, const int* __restrict__ dlen,
                                 const int* __restrict__ enc_cap, const float* __restrict__ emb_W,
                                 const unsigned short* __restrict__ h_bf,
                                 const unsigned short* __restrict__ encbf,
                                 const float* __restrict__ encf, int use_bf,
                                 float* __restrict__ alphas_out, unsigned short* __restrict__ xcat, int t)
{
    int b = blockIdx.y, x = blockIdx.x, tid = threadIdx.x;
    int wave = tid >> 6, lane = tid & 63;
    __shared__ float al[P_];
    __shared__ float red[8];
    float v = (tid < P_) ? sc_in[b * P_ + tid] : -1e30f;
    float m = v;
    #pragma unroll
    for (int off = 32; off; off >>= 1) m = fmaxf(m, __shfl_down(m, off));
    if (lane == 0) red[wave] = m;
    __syncthreads();
    if (tid == 0) {
        float mm = red[0];
        for (int w = 1; w < 4; ++w) mm = fmaxf(mm, red[w]);
        red[4] = mm;
    }
    __syncthreads();
    m = red[4];
    float e = (tid < P_) ? __expf(v - m) : 0.f;
    float s = e;
    #pragma unroll
    for (int off = 32; off; off >>= 1) s += __shfl_down(s, off);
    if (lane == 0) red[wave] = s;
    __syncthreads();
    if (tid == 0) {
        float s2 = 0.f;
        for (int w = 0; w < 4; ++w) s2 += red[w];
        red[5] = 1.0f / s2;
    }
    __syncthreads();
    float inv = red[5];
    if (tid < P_) al[tid] = e * inv;
    __syncthreads();

    int sb = si[b];
    float af = (dlen[b] > t) ? 1.0f : 0.0f;
    if (x == 0) {
        if (tid < P_) alphas_out[((size_t)b * TT + t) * P_ + tid] = al[tid] * af;
        int tok = enc_cap[sb * LL + t];
        for (int k = tid; k < EE; k += 256) {
            xcat[(size_t)b * XKK + k]        = f2bf(emb_W[(size_t)tok * EE + k]);
            xcat[(size_t)b * XKK + 2560 + k] = h_bf[b * DD + k];
        }
    }

    int e0 = x * 512 + tid * 2;
    float a0 = 0.f, a1 = 0.f;
    if (use_bf) {
        const unsigned short* base = encbf + (size_t)sb * P_ * ENCD + e0;
        #pragma unroll 4
        for (int p = 0; p < P_; ++p) {
            unsigned int u = *(const unsigned int*)(base + (size_t)p * ENCD);
            a0 = fmaf(al[p], __uint_as_float(u << 16), a0);
            a1 = fmaf(al[p], __uint_as_float(u & 0xffff0000u), a1);
        }
    } else {
        const float* base = encf + (size_t)sb * P_ * ENCD + e0;
        #pragma unroll 4
        for (int p = 0; p < P_; ++p) {
            float2 u = *(const float2*)(base + (size_t)p * ENCD);
            a0 = fmaf(al[p], u.x, a0);
            a1 = fmaf(al[p], u.y, a1);
        }
    }
    const float* p0 = proj + (size_t)b * PROJN;
    const float* p1 = proj + (size_t)B_ * PROJN + (size_t)b * PROJN;
    float g0 = sigmoidf_(p0[AA + e0]     + p1[AA + e0]     + battn[AA + e0]);
    float g1 = sigmoidf_(p0[AA + e0 + 1] + p1[AA + e0 + 1] + battn[AA + e0 + 1]);
    unsigned int pk = (unsigned int)f2bf(a0 * g0) | ((unsigned int)f2bf(a1 * g1) << 16);
    *(unsigned int*)&xcat[(size_t)b * XKK + EE + e0] = pk;
}

// ---------------------------------------------------------------------------
// LSTM pointwise for step (t-1): sum 4 gate slabs + bias -> h,c update
// ---------------------------------------------------------------------------
__global__ void pointwise_kernel(const float* __restrict__ gates, const float* __restrict__ blstm,
                                 const int* __restrict__ dlen,
                                 float* __restrict__ h, float* __restrict__ c,
                                 unsigned short* __restrict__ h_bf, unsigned short* __restrict__ hstore,
                                 int t)
{
    int idx = blockIdx.x * 256 + threadIdx.x;   // B*D
    int b = idx >> 9, d = idx & 511;
    const size_t slab = (size_t)B_ * 2048;
    const float* g = gates + (size_t)b * 2048;
    float gi = blstm[d], gf = blstm[512 + d], gg = blstm[1024 + d], go = blstm[1536 + d];
    #pragma unroll
    for (int z = 0; z < 4; ++z) {
        gi += g[z * slab + d];
        gf += g[z * slab + 512 + d];
        gg += g[z * slab + 1024 + d];
        go += g[z * slab + 1536 + d];
    }
    float cn = sigmoidf_(gf) * c[idx] + sigmoidf_(gi) * tanhf(gg);
    float hn = sigmoidf_(go) * tanhf(cn);
    hstore[((size_t)(t - 1) * B_ + b) * DD + d] = f2bf(hn);
    bool act = dlen[b] > (t - 1);
    float hv = act ? hn : h[idx];
    float cv = act ? cn : c[idx];
    h[idx] = hv; c[idx] = cv;
    h_bf[idx] = f2bf(hv);
}

// ---------------------------------------------------------------------------
// converts
// ---------------------------------------------------------------------------
__global__ void conv_bf16_kernel(const float* __restrict__ src, unsigned short* __restrict__ dst, int n4)
{
    for (int i = blockIdx.x * 256 + threadIdx.x; i < n4; i += gridDim.x * 256) {
        float4 v = ((const float4*)src)[i];
        ushort4 o;
        o.x = f2bf(v.x); o.y = f2bf(v.y); o.z = f2bf(v.z); o.w = f2bf(v.w);
        ((ushort4*)dst)[i] = o;
    }
}
__global__ void conv_wproj_kernel(const float* __restrict__ dec_W, const float* __restrict__ fbeta_W,
                                  unsigned short* __restrict__ dst)
{   // grid (2, 2560)
    int k = blockIdx.x * 256 + threadIdx.x, n = blockIdx.y;
    float v = (n < AA) ? dec_W[(size_t)n * DD + k] : fbeta_W[(size_t)(n - AA) * DD + k];
    dst[(size_t)n * DD + k] = f2bf(v);
}
__global__ void conv_wcat_kernel(const float* __restrict__ Wih, const float* __restrict__ Whh,
                                 unsigned short* __restrict__ dst)
{   // grid (12, 2048)
    int k = blockIdx.x * 256 + threadIdx.x, n = blockIdx.y;
    float v = (k < 2560) ? Wih[(size_t)n * 2560 + k] : Whh[(size_t)n * DD + (k - 2560)];
    dst[(size_t)n * XKK + k] = f2bf(v);
}
__global__ void conv_fcw_kernel(const float* __restrict__ fc_W, unsigned short* __restrict__ dst)
{   // grid (2, 10048)
    int k = blockIdx.x * 256 + threadIdx.x, n = blockIdx.y;
    float v = (n < VV) ? fc_W[(size_t)n * DD + k] : 0.f;
    dst[(size_t)n * DD + k] = f2bf(v);
}

// ---------------------------------------------------------------------------
extern "C" void kernel_launch(void* const* d_in, const int* in_sizes, int n_in,
                              void* d_out, int out_size, void* d_ws, size_t ws_size,
                              hipStream_t stream)
{
    const float* encoder_out = (const float*)d_in[0];
    const int*   enc_cap     = (const int*)d_in[1];
    const int*   cap_len     = (const int*)d_in[2];
    const float* emb_W       = (const float*)d_in[3];
    const float* init_h_W    = (const float*)d_in[4];
    const float* init_h_b    = (const float*)d_in[5];
    const float* init_c_W    = (const float*)d_in[6];
    const float* init_c_b    = (const float*)d_in[7];
    const float* enc_attn_W  = (const float*)d_in[8];
    const float* enc_attn_b  = (const float*)d_in[9];
    const float* dec_attn_W  = (const float*)d_in[10];
    const float* dec_attn_b  = (const float*)d_in[11];
    const float* full_attn_W = (const float*)d_in[12];
    const float* full_attn_b = (const float*)d_in[13];
    const float* lstm_Wih    = (const float*)d_in[14];
    const float* lstm_Whh    = (const float*)d_in[15];
    const float* lstm_bih    = (const float*)d_in[16];
    const float* lstm_bhh    = (const float*)d_in[17];
    const float* fbeta_W     = (const float*)d_in[18];
    const float* fbeta_b     = (const float*)d_in[19];
    const float* fc_W        = (const float*)d_in[20];
    const float* fc_b        = (const float*)d_in[21];

    char* wsb = (char*)d_ws;
    int*   si     = (int*)(wsb + WS_SI);
    int*   dlen   = (int*)(wsb + WS_DLEN);
    float* battn  = (float*)(wsb + WS_BATTN);
    float* blstm  = (float*)(wsb + WS_BLSTM);
    float* means  = (float*)(wsb + WS_MEANS);
    float* sc     = (float*)(wsb + WS_MEANS);   // reuse (init-only vs loop-only)
    float* h      = (float*)(wsb + WS_H);
    float* c      = (float*)(wsb + WS_C);
    unsigned short* h_bf   = (unsigned short*)(wsb + WS_HBF);
    float* proj   = (float*)(wsb + WS_PROJ);
    unsigned short* xcat   = (unsigned short*)(wsb + WS_XCAT);
    float* gates  = (float*)(wsb + WS_GATES);
    unsigned short* hstore = (unsigned short*)(wsb + WS_HSTORE);
    unsigned short* wproj  = (unsigned short*)(wsb + WS_WPROJ);
    unsigned short* wcat   = (unsigned short*)(wsb + WS_WCAT);
    unsigned short* fcw    = (unsigned short*)(wsb + WS_FCW);
    unsigned short* wenc   = (unsigned short*)(wsb + WS_WENC);
    unsigned short* efeat  = (unsigned short*)(wsb + WS_EFEAT);
    unsigned short* encbf  = (unsigned short*)(wsb + WS_ENCBF);

    float* out      = (float*)d_out;
    float* out0     = out + OUT0_OFF;
    float* out_caps = out + OUT1_OFF;
    float* out_dlen = out + OUT2_OFF;
    float* alphas   = out + OUT3_OFF;
    float* out_sind = out + OUT4_OFF;

    const int use_encbf = (ws_size >= NEED_ENCBF) ? 1 : 0;

    // ---- setup ----
    sort_kernel<<<1, B_, 0, stream>>>(cap_len, enc_cap, si, dlen, out_caps, out_dlen, out_sind);
    bias_cat_kernel<<<10, 256, 0, stream>>>(dec_attn_b, fbeta_b, lstm_bih, lstm_bhh, battn, blstm);
    enc_mean_sorted<<<(B_ * ENCD) / 256, 256, 0, stream>>>(encoder_out, si, means);

    // h0/c0 via MFMA CONV path (f32 in, f32 out), K=2048
    mfma_gemm<0, true><<<dim3(DD / 64, 1, 1), 256, 0, stream>>>(
        means, init_h_W, init_h_b, nullptr, h, nullptr, ENCD, ENCD, DD, 0, DD);
    mfma_gemm<0, true><<<dim3(DD / 64, 1, 1), 256, 0, stream>>>(
        means, init_c_W, init_c_b, nullptr, c, nullptr, ENCD, ENCD, DD, 0, DD);
    conv_bf16_kernel<<<64, 256, 0, stream>>>(h, h_bf, (B_ * DD) / 4);

    conv_wproj_kernel<<<dim3(2, PROJN), 256, 0, stream>>>(dec_attn_W, fbeta_W, wproj);
    conv_wcat_kernel<<<dim3(12, 2048), 256, 0, stream>>>(lstm_Wih, lstm_Whh, wcat);
    conv_fcw_kernel<<<dim3(2, VPAD), 256, 0, stream>>>(fc_W, fcw);
    conv_bf16_kernel<<<256, 256, 0, stream>>>(enc_attn_W, wenc, (AA * ENCD) / 4);
    if (use_encbf)
        conv_bf16_kernel<<<2048, 256, 0, stream>>>(encoder_out, encbf, (B_ * P_ * ENCD) / 4);

    // enc_feat -> efeat bf16
    if (use_encbf)
        mfma_gemm<1, false><<<dim3(AA / 64, (B_ * P_) / 128, 1), 256, 0, stream>>>(
            encbf, wenc, enc_attn_b, nullptr, nullptr, efeat, ENCD, ENCD, AA, 0, AA);
    else
        mfma_gemm<1, true><<<dim3(AA / 64, (B_ * P_) / 128, 1), 256, 0, stream>>>(
            encoder_out, enc_attn_W, enc_attn_b, nullptr, nullptr, efeat, ENCD, ENCD, AA, 0, AA);

    // ---- decode loop ----
    for (int t = 0; t < TT; ++t) {
        if (t > 0)
            pointwise_kernel<<<(B_ * DD) / 256, 256, 0, stream>>>(gates, blstm, dlen, h, c, h_bf, hstore, t);

        // proj = h_bf @ [dec_attn|fbeta]^T : split-K x2 slabs (bias in consumers)
        mfma_gemm<0, false><<<dim3(PROJN / 64, 1, 2), 256, 0, stream>>>(
            h_bf, wproj, nullptr, nullptr, proj, nullptr, DD, 256, PROJN, (long long)B_ * PROJN, PROJN);

        scores_raw_kernel<<<dim3(B_, 4), 256, 0, stream>>>(
            efeat, proj, battn, full_attn_W, full_attn_b, si, sc);

        ctx_fused_kernel<<<dim3(4, B_), 256, 0, stream>>>(
            sc, proj, battn, si, dlen, enc_cap, emb_W, h_bf,
            encbf, encoder_out, use_encbf, alphas, xcat, t);

        // gates = x_cat @ [Wih|Whh]^T : split-K x4 slabs (bias in pointwise)
        mfma_gemm<0, false><<<dim3(2048 / 64, 1, 4), 256, 0, stream>>>(
            xcat, wcat, nullptr, nullptr, gates, nullptr, XKK, 768, 2048, (long long)B_ * 2048, 2048);
    }
    pointwise_kernel<<<(B_ * DD) / 256, 256, 0, stream>>>(gates, blstm, dlen, h, c, h_bf, hstore, TT);

    // fc over all steps: out[b,t,:] = (hstore[t,b,:] @ fc_W^T + fc_b) * (dlen[b] > t)
    // grid swapped (t fast-varying in x) so consecutive blocks share the same W panel.
    mfma_gemm<2, false><<<dim3(TT, VPAD / 64, 1), 256, 0, stream>>>(
        hstore, fcw, fc_b, dlen, out0, nullptr, DD, DD, VV, 0, VV);
}